// Round 4
// baseline (6500.717 us; speedup 1.0000x reference)
//
#include <hip/hip_runtime.h>
#include <stdint.h>
#include <math.h>

// =====================================================================
// NeuS renderer — bit-faithful JAX threefry RNG (partitionable mode).
// R4: OUTPUT IS FP32 (reference computes float32 end-to-end; R1-R3 wrongly
// wrote bf16 element stores -> landed in low halves of f32 slots -> read
// back as denormals ~ 0 -> exact-344064 absmax signature every round).
// Pipeline = R3 structure. Diag: out[0] = -2^(30+s) for first failing
// stage s (1..6) iff unhealthy; host guards encode via memset patterns.
// =====================================================================

#define NS    512
#define NB    128
#define NCS   257
#define NPS   32
#define NFS   289
#define NFM   288
#define HID   64

// output element offsets (fp32 elements), reference return order
#define O_HISTS  0
#define O_SDF    4096
#define O_NORMAL 5312512
#define O_ALPHA  21237760
#define O_T      26546176
#define O_W      31854592
#define O_BA     37163008
#define O_BW     39522304
#define O_OP     41881600
#define O_RPDF   41900032
#define O_SPDF   41916416
#define OUT_ELEMS 44013568

// dec[] layout (fp32 canonical inputs in ws)
#define DEC_RT   0
#define DEC_W1   384
#define DEC_B1   576
#define DEC_W2   640
#define DEC_B2   704
#define DEC_INVS 705
#define DEC_RHO  706

// ---------------- threefry2x32 -------------------------------------------
__host__ __device__ inline void tf2x32(uint32_t k0, uint32_t k1,
                                       uint32_t x0, uint32_t x1,
                                       uint32_t& o0, uint32_t& o1) {
  uint32_t ks2 = k0 ^ k1 ^ 0x1BD11BDAu;
  x0 += k0; x1 += k1;
#define TFR(r) { x0 += x1; x1 = (x1 << (r)) | (x1 >> (32 - (r))); x1 ^= x0; }
  TFR(13) TFR(15) TFR(26) TFR(6)
  x0 += k1;  x1 += ks2 + 1u;
  TFR(17) TFR(29) TFR(16) TFR(24)
  x0 += ks2; x1 += k0 + 2u;
  TFR(13) TFR(15) TFR(26) TFR(6)
  x0 += k0;  x1 += k1 + 3u;
  TFR(17) TFR(29) TFR(16) TFR(24)
  x0 += k1;  x1 += ks2 + 4u;
  TFR(13) TFR(15) TFR(26) TFR(6)
  x0 += ks2; x1 += k0 + 5u;
#undef TFR
  o0 = x0; o1 = x1;
}

__device__ inline uint32_t rbits(uint2 k, uint32_t i) {
  uint32_t a, b; tf2x32(k.x, k.y, 0u, i, a, b);
  return a ^ b;   // partitionable 32-bit draw
}

__device__ inline float u01(uint32_t bits) {
  return __uint_as_float(0x3f800000u | (bits >> 9)) - 1.0f;
}
__device__ inline float gumbelf(uint32_t bits) {
  float f = u01(bits);
  float u = (f > 0.0f) ? f : 1.17549435082228751e-38f;
  return -logf(-logf(u));
}
__device__ inline float sigmoidf_(float x) {
  return __fdiv_rn(1.0f, __fadd_rn(1.0f, expf(-x)));
}
__device__ inline float softplusf_(float x) {
  return __fadd_rn(fmaxf(x, 0.0f), log1pf(expf(-fabsf(x))));
}
__device__ inline void argmax_reduce64(float& best, int& bi) {
  for (int off = 1; off < 64; off <<= 1) {
    float ob = __shfl_xor(best, off);
    int   oi = __shfl_xor(bi, off);
    if (ob > best || (ob == best && oi < bi)) { best = ob; bi = oi; }
  }
}

// ---------------- host key derivation (jax.random.split) ------------------
static void jax_split(const uint32_t k[2], int n, uint32_t out[][2]) {
  for (int j = 0; j < n; j++)
    tf2x32(k[0], k[1], 0u, (uint32_t)j, out[j][0], out[j][1]);
}
static inline uint2 mkk(const uint32_t k[2]) { return make_uint2(k[0], k[1]); }

// ======================= kernels ==========================================
__device__ inline float ld_as(const void* p, int i, int isbf) {
  if (isbf) {
    uint16_t h = ((const uint16_t*)p)[i];
    return __uint_as_float(((uint32_t)h) << 16);
  }
  return ((const float*)p)[i];
}

// detect input dtype (fp32 vs bf16) via R-row orthonormality, decode to dec[]
__global__ void k_decode(const void* Rt, const void* W1, const void* b1,
                         const void* w2, const void* b2, const void* invs,
                         const void* rho, float* dec) {
  __shared__ int sflag;
  if (threadIdx.x == 0) {
    float errF = 0.0f, errB = 0.0f;
    for (int v = 0; v < 8; v++)
      for (int row = 0; row < 3; row++) {
        float nF = 0.0f, nB = 0.0f;
        for (int j = 0; j < 3; j++) {
          float aF = ld_as(Rt, v * 12 + row * 4 + j, 0); nF += aF * aF;
          float aB = ld_as(Rt, v * 12 + row * 4 + j, 1); nB += aB * aB;
        }
        errF += fabsf(nF - 1.0f); errB += fabsf(nB - 1.0f);
      }
    int pickF = (errF == errF) && (!(errB == errB) || errF < errB);
    sflag = pickF ? 0 : 1;
  }
  __syncthreads();
  int f = sflag, t = threadIdx.x;
  for (int i = t; i < 384; i += 256) dec[DEC_RT + i] = ld_as(Rt, i, f);
  if (t < 192) dec[DEC_W1 + t] = ld_as(W1, t, f);
  if (t < 64)  dec[DEC_B1 + t] = ld_as(b1, t, f);
  if (t < 64)  dec[DEC_W2 + t] = ld_as(w2, t, f);
  if (t == 0) {
    dec[DEC_B2]   = ld_as(b2, 0, f);
    dec[DEC_INVS] = ld_as(invs, 0, f);
    dec[DEC_RHO]  = ld_as(rho, 0, f);
  }
}

__global__ void k_zero(int* __restrict__ cnts) {
  int i = blockIdx.x * 256 + threadIdx.x;
  if (i < 16384) cnts[i] = 0;
}

// one 64-lane block per coarse ray
__global__ void __launch_bounds__(64) k_coarse(
    const float* __restrict__ dec,
    uint2 k_ru, uint2 k_rv, uint2 k_eta, float mc, float omc,
    float* __restrict__ c_step_pdf, float* __restrict__ c_ray_pdf,
    float* __restrict__ out) {
  int r = blockIdx.x, v = blockIdx.y, lane = threadIdx.x;
  __shared__ float sW[320];                 // W1 192 | b1 64 | w2 64
  __shared__ float ss[NCS], ssdf[NCS], salpha[256];
  for (int i = lane; i < 320; i += 64) sW[i] = dec[DEC_W1 + i];
  float b2 = dec[DEC_B2];

  uint32_t li = (uint32_t)(v * NS + r);
  float un = (float)(r >> 3), vn = (float)(r & 7);
  float ru = __fdiv_rn(__fadd_rn(un, u01(rbits(k_ru, li))), 64.0f);
  float rv = __fdiv_rn(__fadd_rn(vn, u01(rbits(k_rv, li))), 8.0f);
  float phi = __fmul_rn(ru, (float)(2.0 * M_PI));
  float ct  = __fadd_rn(__fmul_rn(rv, omc), mc);
  float stq = sqrtf(fmaxf(__fsub_rn(1.0f, __fmul_rn(ct, ct)), 0.0f));
  float dc0 = __fmul_rn(stq, cosf(phi));
  float dc1 = __fmul_rn(stq, sinf(phi));
  const float* Rv = dec + DEC_RT + v * 12;
  float o0 = Rv[3], o1 = Rv[7], o2 = Rv[11];
  float d0 = dc0 * Rv[0] + dc1 * Rv[1] + ct * Rv[2];
  float d1 = dc0 * Rv[4] + dc1 * Rv[5] + ct * Rv[6];
  float d2 = dc0 * Rv[8] + dc1 * Rv[9] + ct * Rv[10];
  __syncthreads();

  for (int p = lane; p < NCS; p += 64) {
    float sp;
    if (p == 256) sp = __fmul_rn(0.015f, 128.0f);
    else {
      int b = p >> 1;
      float eb = __fmul_rn(0.015f, (float)b);
      if (p & 1) {
        float u = u01(rbits(k_eta, li * 128u + (uint32_t)b));
        sp = __fadd_rn(eb, __fmul_rn(u, 0.015f));
      } else sp = eb;
    }
    ss[p] = sp;
    float px = __fadd_rn(o0, __fmul_rn(sp, d0));
    float py = __fadd_rn(o1, __fmul_rn(sp, d1));
    float pz = __fadd_rn(o2, __fmul_rn(sp, d2));
    float acc = 0.0f;
    for (int j = 0; j < HID; j++) {
      float t = fmaf(px, sW[j], fmaf(py, sW[64 + j], fmaf(pz, sW[128 + j], sW[192 + j])));
      acc = fmaf(softplusf_(t), sW[256 + j], acc);
    }
    ssdf[p] = __fadd_rn(acc, b2);
  }
  __syncthreads();

  for (int p = lane; p < 256; p += 64) {
    float s0 = ss[p], s1 = ss[p + 1];
    float f0 = ssdf[p], f1 = ssdf[p + 1];
    float delta = __fsub_rn(s1, s0);
    float mid_sdf = __fmul_rn(0.5f, __fadd_rn(f1, f0));
    float cosv = __fdiv_rn(__fsub_rn(f1, f0), __fadd_rn(delta, 1e-6f));
    float pcos = 0.0f;
    if (p > 0)
      pcos = __fdiv_rn(__fsub_rn(f0, ssdf[p - 1]),
                       __fadd_rn(__fsub_rn(s0, ss[p - 1]), 1e-6f));
    float cc = fminf(fmaxf(fminf(pcos, cosv), -1000.0f), 0.0f);
    float dsdf = __fmul_rn(__fmul_rn(0.5f, cc), delta);
    float pT = sigmoidf_(__fmul_rn(64.0f, __fsub_rn(mid_sdf, dsdf)));
    float nT = sigmoidf_(__fmul_rn(64.0f, __fadd_rn(mid_sdf, dsdf)));
    // mid_pts exactly as ref: 0.5*(pts[p] + pts[p+1])
    float ax = __fadd_rn(o0, __fmul_rn(s0, d0)), bx = __fadd_rn(o0, __fmul_rn(s1, d0));
    float ay = __fadd_rn(o1, __fmul_rn(s0, d1)), by = __fadd_rn(o1, __fmul_rn(s1, d1));
    float az = __fadd_rn(o2, __fmul_rn(s0, d2)), bz = __fadd_rn(o2, __fmul_rn(s1, d2));
    float mx = __fmul_rn(0.5f, __fadd_rn(ax, bx));
    float my = __fmul_rn(0.5f, __fadd_rn(ay, by));
    float mz = __fmul_rn(0.5f, __fadd_rn(az, bz));
    float n2 = __fadd_rn(__fadd_rn(__fmul_rn(mx, mx), __fmul_rn(my, my)), __fmul_rn(mz, mz));
    bool ins = (sqrtf(n2) < 1.0f) && (mz > 0.0f);
    salpha[p] = __fmul_rn(__fsub_rn(1.0f, __fdiv_rn(nT, __fadd_rn(pT, 1e-6f))),
                          ins ? 1.0f : 0.0f);
  }
  __syncthreads();

  if (lane == 0) {
    float T = 1.0f, rsum = 0.0f;
    int base = (v * NS + r) * NB;
    for (int b = 0; b < NB; b++) {
      float a0 = salpha[2 * b], a1 = salpha[2 * b + 1];
      float w0 = __fmul_rn(a0, T);
      float om = __fsub_rn(1.0f, a0);
      T = __fmul_rn(T, __fadd_rn(__fmul_rn(om, om), 1e-6f));
      float w1 = __fmul_rn(a1, T);
      om = __fsub_rn(1.0f, a1);
      T = __fmul_rn(T, __fadd_rn(__fmul_rn(om, om), 1e-6f));
      float spdf = __fadd_rn(w0, w1);
      c_step_pdf[base + b] = spdf;
      out[O_SPDF + base + b] = spdf;
      rsum = __fadd_rn(rsum, spdf);
    }
    c_ray_pdf[v * NS + r] = rsum;
    out[O_RPDF + v * NS + r] = rsum;
  }
}

// one 64-lane block per (p, v): argmax over 512 (gumbel + log(pdf+1e-6))
__global__ void __launch_bounds__(64) k_raycat(
    const float* __restrict__ c_ray_pdf, uint2 kg,
    int* __restrict__ f_idx, int* __restrict__ cnts) {
  int p = blockIdx.x, v = blockIdx.y, lane = threadIdx.x;
  uint32_t rowbase = ((uint32_t)p * 32u + (uint32_t)v) * 512u;
  float best = -INFINITY; int bi = 0;
  for (int n = lane; n < 512; n += 64) {
    float lg = logf(__fadd_rn(c_ray_pdf[v * 512 + n], 1e-6f));
    float val = __fadd_rn(gumbelf(rbits(kg, rowbase + (uint32_t)n)), lg);
    if (val > best) { best = val; bi = n; }
  }
  argmax_reduce64(best, bi);
  if (lane == 0) {
    f_idx[v * 64 + p] = bi;
    atomicAdd(&cnts[v * 512 + bi], 1);
  }
}

// one 64-lane block per (r, v); loop over the 32 pdf-step draws in-block
__global__ void __launch_bounds__(64) k_stepcat(
    const float* __restrict__ c_step_pdf, const int* __restrict__ f_idx,
    uint2 kg, int* __restrict__ bidx) {
  int r = blockIdx.x, v = blockIdx.y, lane = threadIdx.x;
  int n = (r < 512) ? r : f_idx[v * 64 + (r - 512)];
  const float* pdfrow = c_step_pdf + (v * 512 + n) * 128;
  float lg0 = logf(__fadd_rn(pdfrow[lane], 1e-6f));
  float lg1 = logf(__fadd_rn(pdfrow[64 + lane], 1e-6f));
  for (int p = 0; p < 32; p++) {
    uint32_t base = (((uint32_t)p * 32u + (uint32_t)v) * 576u + (uint32_t)r) * 128u;
    float v0 = __fadd_rn(gumbelf(rbits(kg, base + (uint32_t)lane)), lg0);
    float v1 = __fadd_rn(gumbelf(rbits(kg, base + 64u + (uint32_t)lane)), lg1);
    float best = v0; int bi = lane;
    if (v1 > best) { best = v1; bi = 64 + lane; }
    argmax_reduce64(best, bi);
    if (lane == 0) bidx[(v * 576 + r) * 32 + p] = bi;
  }
}

// one 64-lane block per fine ray: steps + merge + MLP render + bins
__global__ void __launch_bounds__(64) k_fine(
    const float* __restrict__ dec, const int* __restrict__ f_idx,
    const int* __restrict__ cnts, const int* __restrict__ bidx,
    uint2 k_ru, uint2 k_rv, uint2 k_rup, uint2 k_rvp, uint2 k_eta, uint2 k_us,
    float mc, float omc, float sa,
    float* __restrict__ rad_rows, float* __restrict__ out) {
  int r = blockIdx.x, v = blockIdx.y, lane = threadIdx.x;
  __shared__ float sW[320];
  __shared__ float sb[NCS], se[NPS], st[NFS];
  __shared__ float sal[NFM], sac[NFM], sT[NFM], smid[NFM];
  __shared__ float bina[NB], binw[NB], binr[NB];
  for (int i = lane; i < 320; i += 64) sW[i] = dec[DEC_W1 + i];
  bina[lane] = 0.0f; binw[lane] = 0.0f; binr[lane] = 0.0f;
  bina[64 + lane] = 0.0f; binw[64 + lane] = 0.0f; binr[64 + lane] = 0.0f;
  float b2 = dec[DEC_B2], inv_s = dec[DEC_INVS], rho = dec[DEC_RHO];

  int n; float ruB, rvB;
  if (r < 512) {
    n = r;
    ruB = u01(rbits(k_ru, (uint32_t)(v * 512 + r)));
    rvB = u01(rbits(k_rv, (uint32_t)(v * 512 + r)));
  } else {
    int p = r - 512;
    n = f_idx[v * 64 + p];
    ruB = u01(rbits(k_rup, (uint32_t)(v * 64 + p)));
    rvB = u01(rbits(k_rvp, (uint32_t)(v * 64 + p)));
  }
  float un = (float)(n >> 3), vn = (float)(n & 7);
  float ru = __fdiv_rn(__fadd_rn(un, ruB), 64.0f);
  float rv = __fdiv_rn(__fadd_rn(vn, rvB), 8.0f);
  float phi = __fmul_rn(ru, (float)(2.0 * M_PI));
  float ct  = __fadd_rn(__fmul_rn(rv, omc), mc);
  float stq = sqrtf(fmaxf(__fsub_rn(1.0f, __fmul_rn(ct, ct)), 0.0f));
  float dc0 = __fmul_rn(stq, cosf(phi));
  float dc1 = __fmul_rn(stq, sinf(phi));
  const float* Rv = dec + DEC_RT + v * 12;
  float o0 = Rv[3], o1 = Rv[7], o2 = Rv[11];
  float d0 = dc0 * Rv[0] + dc1 * Rv[1] + ct * Rv[2];
  float d1 = dc0 * Rv[4] + dc1 * Rv[5] + ct * Rv[6];
  float d2 = dc0 * Rv[8] + dc1 * Rv[9] + ct * Rv[10];
  float wb = __fdiv_rn(1.0f, __fmul_rn(__fadd_rn((float)cnts[v * 512 + n], 1.0f), 512.0f));
  float wray = __fmul_rn(__fmul_rn(wb, ct), sa);

  uint32_t li = (uint32_t)(v * 576 + r);
  for (int p = lane; p < NCS; p += 64) {
    float sp;
    if (p == 256) sp = __fmul_rn(0.015f, 128.0f);
    else {
      int b = p >> 1;
      float eb = __fmul_rn(0.015f, (float)b);
      if (p & 1) {
        float u = u01(rbits(k_eta, li * 128u + (uint32_t)b));
        sp = __fadd_rn(eb, __fmul_rn(u, 0.015f));
      } else sp = eb;
    }
    sb[p] = sp;
  }
  if (lane < NPS) {
    int b = bidx[(v * 576 + r) * 32 + lane];
    float le = __fmul_rn(0.015f, (float)b);
    float u = u01(rbits(k_us, li * 32u + (uint32_t)lane));
    se[lane] = __fadd_rn(le, __fmul_rn(u, 0.015f));
  }
  __syncthreads();
  if (lane == 0) {
    for (int i = 1; i < NPS; i++) {
      float x = se[i]; int j = i - 1;
      while (j >= 0 && se[j] > x) { se[j + 1] = se[j]; j--; }
      se[j + 1] = x;
    }
    int i = 0, j = 0;
    for (int k = 0; k < NFS; k++) {
      bool takeB = (j >= NPS) || (i < NCS && sb[i] <= se[j]);
      st[k] = takeB ? sb[i++] : se[j++];
    }
  }
  __syncthreads();

  size_t obase = (size_t)(v * 576 + r) * NFM;
  for (int p = lane; p < NFM; p += 64) {
    float s0 = st[p], s1 = st[p + 1];
    float delta = __fsub_rn(s1, s0);
    float mid = __fmul_rn(0.5f, __fadd_rn(s1, s0));
    smid[p] = mid;
    float px = __fadd_rn(o0, __fmul_rn(mid, d0));
    float py = __fadd_rn(o1, __fmul_rn(mid, d1));
    float pz = __fadd_rn(o2, __fmul_rn(mid, d2));
    float n2 = __fadd_rn(__fadd_rn(__fmul_rn(px, px), __fmul_rn(py, py)), __fmul_rn(pz, pz));
    bool ins = (sqrtf(n2) < 1.0f) && (pz > 0.0f);
    float insf = ins ? 1.0f : 0.0f;
    float acc = 0.0f, g0 = 0.0f, g1 = 0.0f, g2 = 0.0f;
    for (int j = 0; j < HID; j++) {
      float t = fmaf(px, sW[j], fmaf(py, sW[64 + j], fmaf(pz, sW[128 + j], sW[192 + j])));
      acc = fmaf(softplusf_(t), sW[256 + j], acc);
      float m = __fmul_rn(sigmoidf_(t), sW[256 + j]);
      g0 = fmaf(m, sW[j], g0);
      g1 = fmaf(m, sW[64 + j], g1);
      g2 = fmaf(m, sW[128 + j], g2);
    }
    float sdf = __fmul_rn(__fadd_rn(acc, b2), insf);
    float nx = __fmul_rn(g0, insf), ny = __fmul_rn(g1, insf), nz = __fmul_rn(g2, insf);
    float cosr = d0 * nx + d1 * ny + d2 * nz;
    float ac = -fmaxf(__fadd_rn(__fmul_rn(-cosr, 0.5f), 0.5f), 0.0f);
    float dsdf = __fmul_rn(__fmul_rn(0.5f, ac), delta);
    float pT = sigmoidf_(__fmul_rn(inv_s, __fsub_rn(sdf, dsdf)));
    float nT = sigmoidf_(__fmul_rn(inv_s, __fadd_rn(sdf, dsdf)));
    float alpha = __fmul_rn(__fsub_rn(1.0f, __fdiv_rn(nT, __fadd_rn(pT, 1e-6f))), insf);
    sal[p] = alpha; sac[p] = ac;
    out[O_SDF + obase + p] = sdf;
    size_t nb3 = (obase + p) * 3;
    out[O_NORMAL + nb3]     = nx;
    out[O_NORMAL + nb3 + 1] = ny;
    out[O_NORMAL + nb3 + 2] = nz;
    out[O_ALPHA + obase + p] = alpha;
  }
  __syncthreads();
  if (lane == 0) {
    float T = 1.0f;
    for (int p = 0; p < NFM; p++) {
      sT[p] = T;
      float a = sal[p];
      float wgt = __fmul_rn(a, T);
      float om = __fsub_rn(1.0f, a);
      T = __fmul_rn(T, __fmul_rn(om, om));    // fine chain: no +1e-6
      float mid = smid[p];
      int bi = (int)floorf(__fdiv_rn(mid, 0.015f));
      bi = bi < 0 ? 0 : (bi > 127 ? 127 : bi);
      if ((mid > __fmul_rn((float)bi, 0.015f)) &&
          (mid < __fmul_rn((float)(bi + 1), 0.015f))) {
        bina[bi] = __fadd_rn(bina[bi], a);
        binw[bi] = __fadd_rn(binw[bi], wgt);
        float inner = __fdiv_rn(-sac[p], __fadd_rn(__fmul_rn(mid, mid), 1e-6f));
        binr[bi] = __fadd_rn(binr[bi], __fmul_rn(wgt, __fmul_rn(rho, inner)));
      }
    }
  }
  __syncthreads();
  for (int p = lane; p < NFM; p += 64) {
    out[O_T + obase + p] = sT[p];
    out[O_W + obase + p] = __fmul_rn(sal[p], sT[p]);
  }
  size_t bb = (size_t)(v * 576 + r) * NB;
  for (int b = lane; b < NB; b += 64) {
    out[O_BA + bb + b] = bina[b];
    out[O_BW + bb + b] = binw[b];
    rad_rows[bb + b] = __fmul_rn(binr[b], wray);   // gathered by k_final
  }
  if (lane == 0) {
    float op = 0.0f;
    for (int b = 0; b < NB; b++) op = __fadd_rn(op, binw[b]);
    out[O_OP + (size_t)(v * 576 + r)] = op;
  }
}

// gather hists[v,b] = sum over 576 rays of rad_rows (no float atomics)
__global__ void k_final(const float* __restrict__ rad_rows,
                        float* __restrict__ out) {
  int i = blockIdx.x * 256 + threadIdx.x;
  if (i < 4096) {
    int v = i >> 7, b = i & 127;
    const float* base = rad_rows + (size_t)v * 576 * 128 + b;
    float s = 0.0f;
    for (int r = 0; r < 576; r++) s = __fadd_rn(s, base[(size_t)r * 128]);
    out[O_HISTS + i] = s;
  }
}

// diag: first failing stage s in 1..6 -> out[0] = -2^(30+s); healthy -> no-op
__global__ void __launch_bounds__(256) k_diag(
    const float* __restrict__ dec, const float* __restrict__ c_step_pdf,
    const int* __restrict__ cnts, const float* __restrict__ rad_rows,
    float* __restrict__ out) {
  __shared__ float red[256];
  __shared__ int redi[256];
  int t = threadIdx.x;

  float m = 0.0f;                       // ws pdf path
  for (int i = t; i < 2097152; i += 256) m = fmaxf(m, fabsf(c_step_pdf[i]));
  red[t] = m; __syncthreads();
  for (int s = 128; s; s >>= 1) { if (t < s) red[t] = fmaxf(red[t], red[t + s]); __syncthreads(); }
  float wsmax = red[0]; __syncthreads();

  int ci = 0;                           // raycat atomics
  for (int i = t; i < 16384; i += 256) ci += cnts[i];
  redi[t] = ci; __syncthreads();
  for (int s = 128; s; s >>= 1) { if (t < s) redi[t] += redi[t + s]; __syncthreads(); }
  int csum = redi[0]; __syncthreads();

  m = 0.0f;                             // fine sdf out-readback (sampled)
  for (int i = t * 61; i < 5308416; i += 256 * 61)
    m = fmaxf(m, fabsf(out[O_SDF + i]));
  red[t] = m; __syncthreads();
  for (int s = 128; s; s >>= 1) { if (t < s) red[t] = fmaxf(red[t], red[t + s]); __syncthreads(); }
  float sdfmax = red[0]; __syncthreads();

  m = 0.0f;                             // radiance rows
  for (int i = t; i < 2359296; i += 256) m = fmaxf(m, fabsf(rad_rows[i]));
  red[t] = m; __syncthreads();
  for (int s = 128; s; s >>= 1) { if (t < s) red[t] = fmaxf(red[t], red[t + s]); __syncthreads(); }
  float radmax = red[0]; __syncthreads();

  m = 0.0f;                             // final hists
  for (int i = t; i < 4096; i += 256) m = fmaxf(m, fabsf(out[O_HISTS + i]));
  red[t] = m; __syncthreads();
  for (int s = 128; s; s >>= 1) { if (t < s) red[t] = fmaxf(red[t], red[t + s]); __syncthreads(); }
  float hmax = red[0]; __syncthreads();

  if (t == 0) {
    float r0 = dec[0] * dec[0] + dec[1] * dec[1] + dec[2] * dec[2];
    int s = 0;
    if (!(fabsf(r0 - 1.0f) < 0.1f)) s = 1;       // decode broken
    else if (!(wsmax > 1e-4f))      s = 2;       // coarse/ws broken
    else if (csum != 2048)          s = 3;       // raycat broken
    else if (!(sdfmax > 1e-4f))     s = 4;       // k_fine / out-writes broken
    else if (!(radmax > 1e-10f))    s = 5;       // radiance all zero
    else if (!(hmax > 1e-2f))       s = 6;       // gather broken
    if (s) out[0] = -ldexpf(1.0f, 30 + s);
  }
}

// ======================= launch ===========================================
extern "C" void kernel_launch(void* const* d_in, const int* in_sizes, int n_in,
                              void* d_out, int out_size, void* d_ws, size_t ws_size,
                              hipStream_t stream) {
  float* out = (float*)d_out;

  // deterministic host guards -> magnitude-decodable patterns in out[0]
  const size_t WS_NEED = 5081856u * 4u;   // bytes
  if (n_in != 7) { hipMemsetAsync(d_out, 0x75, 4, stream); return; }
  static const int want[7] = {384, 192, 64, 64, 1, 1, 1};
  for (int i = 0; i < 7; i++)
    if (in_sizes[i] != want[i]) { hipMemsetAsync(d_out, 0x74, 4, stream); return; }
  if (ws_size < WS_NEED) { hipMemsetAsync(d_out, 0x77, 4, stream); return; }
  (void)out_size;

  uint32_t root[2] = {0u, 42u};
  uint32_t kcf[2][2]; jax_split(root, 2, kcf);
  uint32_t ck[2][2];  jax_split(kcf[0], 2, ck);
  uint32_t crk[5][2]; jax_split(ck[0], 5, crk);
  uint32_t csk[3][2]; jax_split(ck[1], 3, csk);
  uint32_t fk2[2][2]; jax_split(kcf[1], 2, fk2);
  uint32_t frk[5][2]; jax_split(fk2[0], 5, frk);
  uint32_t fsk[3][2]; jax_split(fk2[1], 3, fsk);

  float mc  = (float)cos(60.0 * M_PI / 360.0);
  float omc = 1.0f - mc;
  float sa  = (float)(2.0 * M_PI * (1.0 - (double)mc));

  float* ws = (float*)d_ws;
  size_t off = 0;
  float* dec        = ws + off; off += 768;
  float* c_step_pdf = ws + off; off += 2097152;
  float* c_ray_pdf  = ws + off; off += 16384;
  int*   f_idx      = (int*)(ws + off); off += 2048;
  int*   cnts       = (int*)(ws + off); off += 16384;
  int*   bidx       = (int*)(ws + off); off += 589824;
  float* rad_rows   = ws + off; off += 2359296;   // total 5,081,856 floats

  k_decode<<<1, 256, 0, stream>>>(d_in[0], d_in[1], d_in[2], d_in[3],
                                  d_in[4], d_in[5], d_in[6], dec);
  k_zero<<<64, 256, 0, stream>>>(cnts);
  k_coarse<<<dim3(512, 32), 64, 0, stream>>>(dec,
      mkk(crk[0]), mkk(crk[1]), mkk(csk[0]), mc, omc, c_step_pdf, c_ray_pdf, out);
  k_raycat<<<dim3(64, 32), 64, 0, stream>>>(c_ray_pdf, mkk(frk[2]), f_idx, cnts);
  k_stepcat<<<dim3(576, 32), 64, 0, stream>>>(c_step_pdf, f_idx, mkk(fsk[1]), bidx);
  k_fine<<<dim3(576, 32), 64, 0, stream>>>(dec, f_idx, cnts, bidx,
      mkk(frk[0]), mkk(frk[1]), mkk(frk[3]), mkk(frk[4]), mkk(fsk[0]), mkk(fsk[2]),
      mc, omc, sa, rad_rows, out);
  k_final<<<16, 256, 0, stream>>>(rad_rows, out);
  k_diag<<<1, 256, 0, stream>>>(dec, c_step_pdf, cnts, rad_rows, out);
}

// Round 5
// 3260.073 us; speedup vs baseline: 1.9940x; 1.9940x over previous
//
#include <hip/hip_runtime.h>
#include <stdint.h>
#include <math.h>

// =====================================================================
// NeuS renderer — bit-faithful JAX threefry RNG (partitionable mode).
// R5: PASSED in R4 (absmax 512 < 6881). This round: remove k_diag
// (2986 us = 46% of total, single-block serial scan — pure scaffolding).
// Pipeline otherwise identical to the verified R4 kernel.
// =====================================================================

#define NS    512
#define NB    128
#define NCS   257
#define NPS   32
#define NFS   289
#define NFM   288
#define HID   64

// output element offsets (fp32 elements), reference return order
#define O_HISTS  0
#define O_SDF    4096
#define O_NORMAL 5312512
#define O_ALPHA  21237760
#define O_T      26546176
#define O_W      31854592
#define O_BA     37163008
#define O_BW     39522304
#define O_OP     41881600
#define O_RPDF   41900032
#define O_SPDF   41916416

// dec[] layout (fp32 canonical inputs in ws)
#define DEC_RT   0
#define DEC_W1   384
#define DEC_B1   576
#define DEC_W2   640
#define DEC_B2   704
#define DEC_INVS 705
#define DEC_RHO  706

// ---------------- threefry2x32 -------------------------------------------
__host__ __device__ inline void tf2x32(uint32_t k0, uint32_t k1,
                                       uint32_t x0, uint32_t x1,
                                       uint32_t& o0, uint32_t& o1) {
  uint32_t ks2 = k0 ^ k1 ^ 0x1BD11BDAu;
  x0 += k0; x1 += k1;
#define TFR(r) { x0 += x1; x1 = (x1 << (r)) | (x1 >> (32 - (r))); x1 ^= x0; }
  TFR(13) TFR(15) TFR(26) TFR(6)
  x0 += k1;  x1 += ks2 + 1u;
  TFR(17) TFR(29) TFR(16) TFR(24)
  x0 += ks2; x1 += k0 + 2u;
  TFR(13) TFR(15) TFR(26) TFR(6)
  x0 += k0;  x1 += k1 + 3u;
  TFR(17) TFR(29) TFR(16) TFR(24)
  x0 += k1;  x1 += ks2 + 4u;
  TFR(13) TFR(15) TFR(26) TFR(6)
  x0 += ks2; x1 += k0 + 5u;
#undef TFR
  o0 = x0; o1 = x1;
}

__device__ inline uint32_t rbits(uint2 k, uint32_t i) {
  uint32_t a, b; tf2x32(k.x, k.y, 0u, i, a, b);
  return a ^ b;   // partitionable 32-bit draw
}

__device__ inline float u01(uint32_t bits) {
  return __uint_as_float(0x3f800000u | (bits >> 9)) - 1.0f;
}
__device__ inline float gumbelf(uint32_t bits) {
  float f = u01(bits);
  float u = (f > 0.0f) ? f : 1.17549435082228751e-38f;
  return -logf(-logf(u));
}
__device__ inline float sigmoidf_(float x) {
  return __fdiv_rn(1.0f, __fadd_rn(1.0f, expf(-x)));
}
__device__ inline float softplusf_(float x) {
  return __fadd_rn(fmaxf(x, 0.0f), log1pf(expf(-fabsf(x))));
}
__device__ inline void argmax_reduce64(float& best, int& bi) {
  for (int off = 1; off < 64; off <<= 1) {
    float ob = __shfl_xor(best, off);
    int   oi = __shfl_xor(bi, off);
    if (ob > best || (ob == best && oi < bi)) { best = ob; bi = oi; }
  }
}

// ---------------- host key derivation (jax.random.split) ------------------
static void jax_split(const uint32_t k[2], int n, uint32_t out[][2]) {
  for (int j = 0; j < n; j++)
    tf2x32(k[0], k[1], 0u, (uint32_t)j, out[j][0], out[j][1]);
}
static inline uint2 mkk(const uint32_t k[2]) { return make_uint2(k[0], k[1]); }

// ======================= kernels ==========================================
__device__ inline float ld_as(const void* p, int i, int isbf) {
  if (isbf) {
    uint16_t h = ((const uint16_t*)p)[i];
    return __uint_as_float(((uint32_t)h) << 16);
  }
  return ((const float*)p)[i];
}

// detect input dtype (fp32 vs bf16) via R-row orthonormality, decode to dec[]
__global__ void k_decode(const void* Rt, const void* W1, const void* b1,
                         const void* w2, const void* b2, const void* invs,
                         const void* rho, float* dec) {
  __shared__ int sflag;
  if (threadIdx.x == 0) {
    float errF = 0.0f, errB = 0.0f;
    for (int v = 0; v < 8; v++)
      for (int row = 0; row < 3; row++) {
        float nF = 0.0f, nB = 0.0f;
        for (int j = 0; j < 3; j++) {
          float aF = ld_as(Rt, v * 12 + row * 4 + j, 0); nF += aF * aF;
          float aB = ld_as(Rt, v * 12 + row * 4 + j, 1); nB += aB * aB;
        }
        errF += fabsf(nF - 1.0f); errB += fabsf(nB - 1.0f);
      }
    int pickF = (errF == errF) && (!(errB == errB) || errF < errB);
    sflag = pickF ? 0 : 1;
  }
  __syncthreads();
  int f = sflag, t = threadIdx.x;
  for (int i = t; i < 384; i += 256) dec[DEC_RT + i] = ld_as(Rt, i, f);
  if (t < 192) dec[DEC_W1 + t] = ld_as(W1, t, f);
  if (t < 64)  dec[DEC_B1 + t] = ld_as(b1, t, f);
  if (t < 64)  dec[DEC_W2 + t] = ld_as(w2, t, f);
  if (t == 0) {
    dec[DEC_B2]   = ld_as(b2, 0, f);
    dec[DEC_INVS] = ld_as(invs, 0, f);
    dec[DEC_RHO]  = ld_as(rho, 0, f);
  }
}

__global__ void k_zero(int* __restrict__ cnts) {
  int i = blockIdx.x * 256 + threadIdx.x;
  if (i < 16384) cnts[i] = 0;
}

// one 64-lane block per coarse ray
__global__ void __launch_bounds__(64) k_coarse(
    const float* __restrict__ dec,
    uint2 k_ru, uint2 k_rv, uint2 k_eta, float mc, float omc,
    float* __restrict__ c_step_pdf, float* __restrict__ c_ray_pdf,
    float* __restrict__ out) {
  int r = blockIdx.x, v = blockIdx.y, lane = threadIdx.x;
  __shared__ float sW[320];                 // W1 192 | b1 64 | w2 64
  __shared__ float ss[NCS], ssdf[NCS], salpha[256];
  for (int i = lane; i < 320; i += 64) sW[i] = dec[DEC_W1 + i];
  float b2 = dec[DEC_B2];

  uint32_t li = (uint32_t)(v * NS + r);
  float un = (float)(r >> 3), vn = (float)(r & 7);
  float ru = __fdiv_rn(__fadd_rn(un, u01(rbits(k_ru, li))), 64.0f);
  float rv = __fdiv_rn(__fadd_rn(vn, u01(rbits(k_rv, li))), 8.0f);
  float phi = __fmul_rn(ru, (float)(2.0 * M_PI));
  float ct  = __fadd_rn(__fmul_rn(rv, omc), mc);
  float stq = sqrtf(fmaxf(__fsub_rn(1.0f, __fmul_rn(ct, ct)), 0.0f));
  float dc0 = __fmul_rn(stq, cosf(phi));
  float dc1 = __fmul_rn(stq, sinf(phi));
  const float* Rv = dec + DEC_RT + v * 12;
  float o0 = Rv[3], o1 = Rv[7], o2 = Rv[11];
  float d0 = dc0 * Rv[0] + dc1 * Rv[1] + ct * Rv[2];
  float d1 = dc0 * Rv[4] + dc1 * Rv[5] + ct * Rv[6];
  float d2 = dc0 * Rv[8] + dc1 * Rv[9] + ct * Rv[10];
  __syncthreads();

  for (int p = lane; p < NCS; p += 64) {
    float sp;
    if (p == 256) sp = __fmul_rn(0.015f, 128.0f);
    else {
      int b = p >> 1;
      float eb = __fmul_rn(0.015f, (float)b);
      if (p & 1) {
        float u = u01(rbits(k_eta, li * 128u + (uint32_t)b));
        sp = __fadd_rn(eb, __fmul_rn(u, 0.015f));
      } else sp = eb;
    }
    ss[p] = sp;
    float px = __fadd_rn(o0, __fmul_rn(sp, d0));
    float py = __fadd_rn(o1, __fmul_rn(sp, d1));
    float pz = __fadd_rn(o2, __fmul_rn(sp, d2));
    float acc = 0.0f;
    for (int j = 0; j < HID; j++) {
      float t = fmaf(px, sW[j], fmaf(py, sW[64 + j], fmaf(pz, sW[128 + j], sW[192 + j])));
      acc = fmaf(softplusf_(t), sW[256 + j], acc);
    }
    ssdf[p] = __fadd_rn(acc, b2);
  }
  __syncthreads();

  for (int p = lane; p < 256; p += 64) {
    float s0 = ss[p], s1 = ss[p + 1];
    float f0 = ssdf[p], f1 = ssdf[p + 1];
    float delta = __fsub_rn(s1, s0);
    float mid_sdf = __fmul_rn(0.5f, __fadd_rn(f1, f0));
    float cosv = __fdiv_rn(__fsub_rn(f1, f0), __fadd_rn(delta, 1e-6f));
    float pcos = 0.0f;
    if (p > 0)
      pcos = __fdiv_rn(__fsub_rn(f0, ssdf[p - 1]),
                       __fadd_rn(__fsub_rn(s0, ss[p - 1]), 1e-6f));
    float cc = fminf(fmaxf(fminf(pcos, cosv), -1000.0f), 0.0f);
    float dsdf = __fmul_rn(__fmul_rn(0.5f, cc), delta);
    float pT = sigmoidf_(__fmul_rn(64.0f, __fsub_rn(mid_sdf, dsdf)));
    float nT = sigmoidf_(__fmul_rn(64.0f, __fadd_rn(mid_sdf, dsdf)));
    float ax = __fadd_rn(o0, __fmul_rn(s0, d0)), bx = __fadd_rn(o0, __fmul_rn(s1, d0));
    float ay = __fadd_rn(o1, __fmul_rn(s0, d1)), by = __fadd_rn(o1, __fmul_rn(s1, d1));
    float az = __fadd_rn(o2, __fmul_rn(s0, d2)), bz = __fadd_rn(o2, __fmul_rn(s1, d2));
    float mx = __fmul_rn(0.5f, __fadd_rn(ax, bx));
    float my = __fmul_rn(0.5f, __fadd_rn(ay, by));
    float mz = __fmul_rn(0.5f, __fadd_rn(az, bz));
    float n2 = __fadd_rn(__fadd_rn(__fmul_rn(mx, mx), __fmul_rn(my, my)), __fmul_rn(mz, mz));
    bool ins = (sqrtf(n2) < 1.0f) && (mz > 0.0f);
    salpha[p] = __fmul_rn(__fsub_rn(1.0f, __fdiv_rn(nT, __fadd_rn(pT, 1e-6f))),
                          ins ? 1.0f : 0.0f);
  }
  __syncthreads();

  if (lane == 0) {
    float T = 1.0f, rsum = 0.0f;
    int base = (v * NS + r) * NB;
    for (int b = 0; b < NB; b++) {
      float a0 = salpha[2 * b], a1 = salpha[2 * b + 1];
      float w0 = __fmul_rn(a0, T);
      float om = __fsub_rn(1.0f, a0);
      T = __fmul_rn(T, __fadd_rn(__fmul_rn(om, om), 1e-6f));
      float w1 = __fmul_rn(a1, T);
      om = __fsub_rn(1.0f, a1);
      T = __fmul_rn(T, __fadd_rn(__fmul_rn(om, om), 1e-6f));
      float spdf = __fadd_rn(w0, w1);
      c_step_pdf[base + b] = spdf;
      out[O_SPDF + base + b] = spdf;
      rsum = __fadd_rn(rsum, spdf);
    }
    c_ray_pdf[v * NS + r] = rsum;
    out[O_RPDF + v * NS + r] = rsum;
  }
}

// one 64-lane block per (p, v): argmax over 512 (gumbel + log(pdf+1e-6))
__global__ void __launch_bounds__(64) k_raycat(
    const float* __restrict__ c_ray_pdf, uint2 kg,
    int* __restrict__ f_idx, int* __restrict__ cnts) {
  int p = blockIdx.x, v = blockIdx.y, lane = threadIdx.x;
  uint32_t rowbase = ((uint32_t)p * 32u + (uint32_t)v) * 512u;
  float best = -INFINITY; int bi = 0;
  for (int n = lane; n < 512; n += 64) {
    float lg = logf(__fadd_rn(c_ray_pdf[v * 512 + n], 1e-6f));
    float val = __fadd_rn(gumbelf(rbits(kg, rowbase + (uint32_t)n)), lg);
    if (val > best) { best = val; bi = n; }
  }
  argmax_reduce64(best, bi);
  if (lane == 0) {
    f_idx[v * 64 + p] = bi;
    atomicAdd(&cnts[v * 512 + bi], 1);
  }
}

// one 64-lane block per (r, v); loop over the 32 pdf-step draws in-block
__global__ void __launch_bounds__(64) k_stepcat(
    const float* __restrict__ c_step_pdf, const int* __restrict__ f_idx,
    uint2 kg, int* __restrict__ bidx) {
  int r = blockIdx.x, v = blockIdx.y, lane = threadIdx.x;
  int n = (r < 512) ? r : f_idx[v * 64 + (r - 512)];
  const float* pdfrow = c_step_pdf + (v * 512 + n) * 128;
  float lg0 = logf(__fadd_rn(pdfrow[lane], 1e-6f));
  float lg1 = logf(__fadd_rn(pdfrow[64 + lane], 1e-6f));
  for (int p = 0; p < 32; p++) {
    uint32_t base = (((uint32_t)p * 32u + (uint32_t)v) * 576u + (uint32_t)r) * 128u;
    float v0 = __fadd_rn(gumbelf(rbits(kg, base + (uint32_t)lane)), lg0);
    float v1 = __fadd_rn(gumbelf(rbits(kg, base + 64u + (uint32_t)lane)), lg1);
    float best = v0; int bi = lane;
    if (v1 > best) { best = v1; bi = 64 + lane; }
    argmax_reduce64(best, bi);
    if (lane == 0) bidx[(v * 576 + r) * 32 + p] = bi;
  }
}

// one 64-lane block per fine ray: steps + merge + MLP render + bins
__global__ void __launch_bounds__(64) k_fine(
    const float* __restrict__ dec, const int* __restrict__ f_idx,
    const int* __restrict__ cnts, const int* __restrict__ bidx,
    uint2 k_ru, uint2 k_rv, uint2 k_rup, uint2 k_rvp, uint2 k_eta, uint2 k_us,
    float mc, float omc, float sa,
    float* __restrict__ rad_rows, float* __restrict__ out) {
  int r = blockIdx.x, v = blockIdx.y, lane = threadIdx.x;
  __shared__ float sW[320];
  __shared__ float sb[NCS], se[NPS], st[NFS];
  __shared__ float sal[NFM], sac[NFM], sT[NFM], smid[NFM];
  __shared__ float bina[NB], binw[NB], binr[NB];
  for (int i = lane; i < 320; i += 64) sW[i] = dec[DEC_W1 + i];
  bina[lane] = 0.0f; binw[lane] = 0.0f; binr[lane] = 0.0f;
  bina[64 + lane] = 0.0f; binw[64 + lane] = 0.0f; binr[64 + lane] = 0.0f;
  float b2 = dec[DEC_B2], inv_s = dec[DEC_INVS], rho = dec[DEC_RHO];

  int n; float ruB, rvB;
  if (r < 512) {
    n = r;
    ruB = u01(rbits(k_ru, (uint32_t)(v * 512 + r)));
    rvB = u01(rbits(k_rv, (uint32_t)(v * 512 + r)));
  } else {
    int p = r - 512;
    n = f_idx[v * 64 + p];
    ruB = u01(rbits(k_rup, (uint32_t)(v * 64 + p)));
    rvB = u01(rbits(k_rvp, (uint32_t)(v * 64 + p)));
  }
  float un = (float)(n >> 3), vn = (float)(n & 7);
  float ru = __fdiv_rn(__fadd_rn(un, ruB), 64.0f);
  float rv = __fdiv_rn(__fadd_rn(vn, rvB), 8.0f);
  float phi = __fmul_rn(ru, (float)(2.0 * M_PI));
  float ct  = __fadd_rn(__fmul_rn(rv, omc), mc);
  float stq = sqrtf(fmaxf(__fsub_rn(1.0f, __fmul_rn(ct, ct)), 0.0f));
  float dc0 = __fmul_rn(stq, cosf(phi));
  float dc1 = __fmul_rn(stq, sinf(phi));
  const float* Rv = dec + DEC_RT + v * 12;
  float o0 = Rv[3], o1 = Rv[7], o2 = Rv[11];
  float d0 = dc0 * Rv[0] + dc1 * Rv[1] + ct * Rv[2];
  float d1 = dc0 * Rv[4] + dc1 * Rv[5] + ct * Rv[6];
  float d2 = dc0 * Rv[8] + dc1 * Rv[9] + ct * Rv[10];
  float wb = __fdiv_rn(1.0f, __fmul_rn(__fadd_rn((float)cnts[v * 512 + n], 1.0f), 512.0f));
  float wray = __fmul_rn(__fmul_rn(wb, ct), sa);

  uint32_t li = (uint32_t)(v * 576 + r);
  for (int p = lane; p < NCS; p += 64) {
    float sp;
    if (p == 256) sp = __fmul_rn(0.015f, 128.0f);
    else {
      int b = p >> 1;
      float eb = __fmul_rn(0.015f, (float)b);
      if (p & 1) {
        float u = u01(rbits(k_eta, li * 128u + (uint32_t)b));
        sp = __fadd_rn(eb, __fmul_rn(u, 0.015f));
      } else sp = eb;
    }
    sb[p] = sp;
  }
  if (lane < NPS) {
    int b = bidx[(v * 576 + r) * 32 + lane];
    float le = __fmul_rn(0.015f, (float)b);
    float u = u01(rbits(k_us, li * 32u + (uint32_t)lane));
    se[lane] = __fadd_rn(le, __fmul_rn(u, 0.015f));
  }
  __syncthreads();
  if (lane == 0) {
    for (int i = 1; i < NPS; i++) {
      float x = se[i]; int j = i - 1;
      while (j >= 0 && se[j] > x) { se[j + 1] = se[j]; j--; }
      se[j + 1] = x;
    }
    int i = 0, j = 0;
    for (int k = 0; k < NFS; k++) {
      bool takeB = (j >= NPS) || (i < NCS && sb[i] <= se[j]);
      st[k] = takeB ? sb[i++] : se[j++];
    }
  }
  __syncthreads();

  size_t obase = (size_t)(v * 576 + r) * NFM;
  for (int p = lane; p < NFM; p += 64) {
    float s0 = st[p], s1 = st[p + 1];
    float delta = __fsub_rn(s1, s0);
    float mid = __fmul_rn(0.5f, __fadd_rn(s1, s0));
    smid[p] = mid;
    float px = __fadd_rn(o0, __fmul_rn(mid, d0));
    float py = __fadd_rn(o1, __fmul_rn(mid, d1));
    float pz = __fadd_rn(o2, __fmul_rn(mid, d2));
    float n2 = __fadd_rn(__fadd_rn(__fmul_rn(px, px), __fmul_rn(py, py)), __fmul_rn(pz, pz));
    bool ins = (sqrtf(n2) < 1.0f) && (pz > 0.0f);
    float insf = ins ? 1.0f : 0.0f;
    float acc = 0.0f, g0 = 0.0f, g1 = 0.0f, g2 = 0.0f;
    for (int j = 0; j < HID; j++) {
      float t = fmaf(px, sW[j], fmaf(py, sW[64 + j], fmaf(pz, sW[128 + j], sW[192 + j])));
      acc = fmaf(softplusf_(t), sW[256 + j], acc);
      float m = __fmul_rn(sigmoidf_(t), sW[256 + j]);
      g0 = fmaf(m, sW[j], g0);
      g1 = fmaf(m, sW[64 + j], g1);
      g2 = fmaf(m, sW[128 + j], g2);
    }
    float sdf = __fmul_rn(__fadd_rn(acc, b2), insf);
    float nx = __fmul_rn(g0, insf), ny = __fmul_rn(g1, insf), nz = __fmul_rn(g2, insf);
    float cosr = d0 * nx + d1 * ny + d2 * nz;
    float ac = -fmaxf(__fadd_rn(__fmul_rn(-cosr, 0.5f), 0.5f), 0.0f);
    float dsdf = __fmul_rn(__fmul_rn(0.5f, ac), delta);
    float pT = sigmoidf_(__fmul_rn(inv_s, __fsub_rn(sdf, dsdf)));
    float nT = sigmoidf_(__fmul_rn(inv_s, __fadd_rn(sdf, dsdf)));
    float alpha = __fmul_rn(__fsub_rn(1.0f, __fdiv_rn(nT, __fadd_rn(pT, 1e-6f))), insf);
    sal[p] = alpha; sac[p] = ac;
    out[O_SDF + obase + p] = sdf;
    size_t nb3 = (obase + p) * 3;
    out[O_NORMAL + nb3]     = nx;
    out[O_NORMAL + nb3 + 1] = ny;
    out[O_NORMAL + nb3 + 2] = nz;
    out[O_ALPHA + obase + p] = alpha;
  }
  __syncthreads();
  if (lane == 0) {
    float T = 1.0f;
    for (int p = 0; p < NFM; p++) {
      sT[p] = T;
      float a = sal[p];
      float wgt = __fmul_rn(a, T);
      float om = __fsub_rn(1.0f, a);
      T = __fmul_rn(T, __fmul_rn(om, om));    // fine chain: no +1e-6
      float mid = smid[p];
      int bi = (int)floorf(__fdiv_rn(mid, 0.015f));
      bi = bi < 0 ? 0 : (bi > 127 ? 127 : bi);
      if ((mid > __fmul_rn((float)bi, 0.015f)) &&
          (mid < __fmul_rn((float)(bi + 1), 0.015f))) {
        bina[bi] = __fadd_rn(bina[bi], a);
        binw[bi] = __fadd_rn(binw[bi], wgt);
        float inner = __fdiv_rn(-sac[p], __fadd_rn(__fmul_rn(mid, mid), 1e-6f));
        binr[bi] = __fadd_rn(binr[bi], __fmul_rn(wgt, __fmul_rn(rho, inner)));
      }
    }
  }
  __syncthreads();
  for (int p = lane; p < NFM; p += 64) {
    out[O_T + obase + p] = sT[p];
    out[O_W + obase + p] = __fmul_rn(sal[p], sT[p]);
  }
  size_t bb = (size_t)(v * 576 + r) * NB;
  for (int b = lane; b < NB; b += 64) {
    out[O_BA + bb + b] = bina[b];
    out[O_BW + bb + b] = binw[b];
    rad_rows[bb + b] = __fmul_rn(binr[b], wray);   // gathered by k_final
  }
  if (lane == 0) {
    float op = 0.0f;
    for (int b = 0; b < NB; b++) op = __fadd_rn(op, binw[b]);
    out[O_OP + (size_t)(v * 576 + r)] = op;
  }
}

// gather hists[v,b] = sum over 576 rays of rad_rows (no float atomics)
__global__ void k_final(const float* __restrict__ rad_rows,
                        float* __restrict__ out) {
  int i = blockIdx.x * 256 + threadIdx.x;
  if (i < 4096) {
    int v = i >> 7, b = i & 127;
    const float* base = rad_rows + (size_t)v * 576 * 128 + b;
    float s = 0.0f;
    for (int r = 0; r < 576; r++) s = __fadd_rn(s, base[(size_t)r * 128]);
    out[O_HISTS + i] = s;
  }
}

// ======================= launch ===========================================
extern "C" void kernel_launch(void* const* d_in, const int* in_sizes, int n_in,
                              void* d_out, int out_size, void* d_ws, size_t ws_size,
                              hipStream_t stream) {
  float* out = (float*)d_out;

  // host guards (decodable memset patterns; normal path touches nothing)
  const size_t WS_NEED = 5081856u * 4u;
  if (n_in != 7) { hipMemsetAsync(d_out, 0x75, 4, stream); return; }
  static const int want[7] = {384, 192, 64, 64, 1, 1, 1};
  for (int i = 0; i < 7; i++)
    if (in_sizes[i] != want[i]) { hipMemsetAsync(d_out, 0x74, 4, stream); return; }
  if (ws_size < WS_NEED) { hipMemsetAsync(d_out, 0x77, 4, stream); return; }
  (void)out_size;

  uint32_t root[2] = {0u, 42u};
  uint32_t kcf[2][2]; jax_split(root, 2, kcf);
  uint32_t ck[2][2];  jax_split(kcf[0], 2, ck);
  uint32_t crk[5][2]; jax_split(ck[0], 5, crk);
  uint32_t csk[3][2]; jax_split(ck[1], 3, csk);
  uint32_t fk2[2][2]; jax_split(kcf[1], 2, fk2);
  uint32_t frk[5][2]; jax_split(fk2[0], 5, frk);
  uint32_t fsk[3][2]; jax_split(fk2[1], 3, fsk);

  float mc  = (float)cos(60.0 * M_PI / 360.0);
  float omc = 1.0f - mc;
  float sa  = (float)(2.0 * M_PI * (1.0 - (double)mc));

  float* ws = (float*)d_ws;
  size_t off = 0;
  float* dec        = ws + off; off += 768;
  float* c_step_pdf = ws + off; off += 2097152;
  float* c_ray_pdf  = ws + off; off += 16384;
  int*   f_idx      = (int*)(ws + off); off += 2048;
  int*   cnts       = (int*)(ws + off); off += 16384;
  int*   bidx       = (int*)(ws + off); off += 589824;
  float* rad_rows   = ws + off; off += 2359296;   // total 5,081,856 floats

  k_decode<<<1, 256, 0, stream>>>(d_in[0], d_in[1], d_in[2], d_in[3],
                                  d_in[4], d_in[5], d_in[6], dec);
  k_zero<<<64, 256, 0, stream>>>(cnts);
  k_coarse<<<dim3(512, 32), 64, 0, stream>>>(dec,
      mkk(crk[0]), mkk(crk[1]), mkk(csk[0]), mc, omc, c_step_pdf, c_ray_pdf, out);
  k_raycat<<<dim3(64, 32), 64, 0, stream>>>(c_ray_pdf, mkk(frk[2]), f_idx, cnts);
  k_stepcat<<<dim3(576, 32), 64, 0, stream>>>(c_step_pdf, f_idx, mkk(fsk[1]), bidx);
  k_fine<<<dim3(576, 32), 64, 0, stream>>>(dec, f_idx, cnts, bidx,
      mkk(frk[0]), mkk(frk[1]), mkk(frk[3]), mkk(frk[4]), mkk(fsk[0]), mkk(fsk[2]),
      mc, omc, sa, rad_rows, out);
  k_final<<<16, 256, 0, stream>>>(rad_rows, out);
}

// Round 6
// 1199.223 us; speedup vs baseline: 5.4208x; 2.7185x over previous
//
#include <hip/hip_runtime.h>
#include <stdint.h>
#include <math.h>

// =====================================================================
// NeuS renderer — bit-faithful JAX threefry RNG (partitionable mode).
// R6: perf round.
//  - k_fine: parallel merge (position-scatter), inside-point compaction
//    (ballot), fast-math MLP (shared exp, __logf, v_rcp), parallel
//    prefix-product T-scan, LDS-atomic binning, parallel opacity reduce.
//    Outputs-only => fast-math safe vs 2% absolute thresholds.
//  - k_coarse: inside-adjacent point compaction with BITWISE-identical
//    libm math for computed points (coarse feeds categorical samplers —
//    arithmetic there must not change). Serial pdf chain kept exact.
//  - categorical kernels (raycat/stepcat) untouched (libm logf exact).
// =====================================================================

#define NS    512
#define NB    128
#define NCS   257
#define NPS   32
#define NFS   289
#define NFM   288
#define HID   64

// output element offsets (fp32 elements), reference return order
#define O_HISTS  0
#define O_SDF    4096
#define O_NORMAL 5312512
#define O_ALPHA  21237760
#define O_T      26546176
#define O_W      31854592
#define O_BA     37163008
#define O_BW     39522304
#define O_OP     41881600
#define O_RPDF   41900032
#define O_SPDF   41916416

// dec[] layout (fp32 canonical inputs in ws)
#define DEC_RT   0
#define DEC_W1   384
#define DEC_B1   576
#define DEC_W2   640
#define DEC_B2   704
#define DEC_INVS 705
#define DEC_RHO  706

// ---------------- threefry2x32 -------------------------------------------
__host__ __device__ inline void tf2x32(uint32_t k0, uint32_t k1,
                                       uint32_t x0, uint32_t x1,
                                       uint32_t& o0, uint32_t& o1) {
  uint32_t ks2 = k0 ^ k1 ^ 0x1BD11BDAu;
  x0 += k0; x1 += k1;
#define TFR(r) { x0 += x1; x1 = (x1 << (r)) | (x1 >> (32 - (r))); x1 ^= x0; }
  TFR(13) TFR(15) TFR(26) TFR(6)
  x0 += k1;  x1 += ks2 + 1u;
  TFR(17) TFR(29) TFR(16) TFR(24)
  x0 += ks2; x1 += k0 + 2u;
  TFR(13) TFR(15) TFR(26) TFR(6)
  x0 += k0;  x1 += k1 + 3u;
  TFR(17) TFR(29) TFR(16) TFR(24)
  x0 += k1;  x1 += ks2 + 4u;
  TFR(13) TFR(15) TFR(26) TFR(6)
  x0 += ks2; x1 += k0 + 5u;
#undef TFR
  o0 = x0; o1 = x1;
}

__device__ inline uint32_t rbits(uint2 k, uint32_t i) {
  uint32_t a, b; tf2x32(k.x, k.y, 0u, i, a, b);
  return a ^ b;
}

__device__ inline float u01(uint32_t bits) {
  return __uint_as_float(0x3f800000u | (bits >> 9)) - 1.0f;
}
__device__ inline float gumbelf(uint32_t bits) {
  float f = u01(bits);
  float u = (f > 0.0f) ? f : 1.17549435082228751e-38f;
  return -logf(-logf(u));
}
__device__ inline float sigmoidf_(float x) {           // libm-exact
  return __fdiv_rn(1.0f, __fadd_rn(1.0f, expf(-x)));
}
__device__ inline float softplusf_(float x) {          // libm-exact
  return __fadd_rn(fmaxf(x, 0.0f), log1pf(expf(-fabsf(x))));
}
// fast variants (k_fine only — outputs, not samplers)
__device__ inline float frcp_(float x) { return __builtin_amdgcn_rcpf(x); }
__device__ inline float fsig_(float x) {               // fast sigmoid
  return frcp_(1.0f + __expf(-x));
}
__device__ inline void argmax_reduce64(float& best, int& bi) {
  for (int off = 1; off < 64; off <<= 1) {
    float ob = __shfl_xor(best, off);
    int   oi = __shfl_xor(bi, off);
    if (ob > best || (ob == best && oi < bi)) { best = ob; bi = oi; }
  }
}

// ---------------- host key derivation (jax.random.split) ------------------
static void jax_split(const uint32_t k[2], int n, uint32_t out[][2]) {
  for (int j = 0; j < n; j++)
    tf2x32(k[0], k[1], 0u, (uint32_t)j, out[j][0], out[j][1]);
}
static inline uint2 mkk(const uint32_t k[2]) { return make_uint2(k[0], k[1]); }

// ======================= kernels ==========================================
__device__ inline float ld_as(const void* p, int i, int isbf) {
  if (isbf) {
    uint16_t h = ((const uint16_t*)p)[i];
    return __uint_as_float(((uint32_t)h) << 16);
  }
  return ((const float*)p)[i];
}

__global__ void k_decode(const void* Rt, const void* W1, const void* b1,
                         const void* w2, const void* b2, const void* invs,
                         const void* rho, float* dec) {
  __shared__ int sflag;
  if (threadIdx.x == 0) {
    float errF = 0.0f, errB = 0.0f;
    for (int v = 0; v < 8; v++)
      for (int row = 0; row < 3; row++) {
        float nF = 0.0f, nB = 0.0f;
        for (int j = 0; j < 3; j++) {
          float aF = ld_as(Rt, v * 12 + row * 4 + j, 0); nF += aF * aF;
          float aB = ld_as(Rt, v * 12 + row * 4 + j, 1); nB += aB * aB;
        }
        errF += fabsf(nF - 1.0f); errB += fabsf(nB - 1.0f);
      }
    int pickF = (errF == errF) && (!(errB == errB) || errF < errB);
    sflag = pickF ? 0 : 1;
  }
  __syncthreads();
  int f = sflag, t = threadIdx.x;
  for (int i = t; i < 384; i += 256) dec[DEC_RT + i] = ld_as(Rt, i, f);
  if (t < 192) dec[DEC_W1 + t] = ld_as(W1, t, f);
  if (t < 64)  dec[DEC_B1 + t] = ld_as(b1, t, f);
  if (t < 64)  dec[DEC_W2 + t] = ld_as(w2, t, f);
  if (t == 0) {
    dec[DEC_B2]   = ld_as(b2, 0, f);
    dec[DEC_INVS] = ld_as(invs, 0, f);
    dec[DEC_RHO]  = ld_as(rho, 0, f);
  }
}

__global__ void k_zero(int* __restrict__ cnts) {
  int i = blockIdx.x * 256 + threadIdx.x;
  if (i < 16384) cnts[i] = 0;
}

// one 64-lane block per coarse ray — EXACT math for all computed values
__global__ void __launch_bounds__(64) k_coarse(
    const float* __restrict__ dec,
    uint2 k_ru, uint2 k_rv, uint2 k_eta, float mc, float omc,
    float* __restrict__ c_step_pdf, float* __restrict__ c_ray_pdf,
    float* __restrict__ out) {
  int r = blockIdx.x, v = blockIdx.y, lane = threadIdx.x;
  __shared__ float sW[320];
  __shared__ float ss[NCS], ssdf[NCS], salpha[256], sflagf[256];
  __shared__ int   slist[NCS];
  for (int i = lane; i < 320; i += 64) sW[i] = dec[DEC_W1 + i];
  float b2 = dec[DEC_B2];

  uint32_t li = (uint32_t)(v * NS + r);
  float un = (float)(r >> 3), vn = (float)(r & 7);
  float ru = __fdiv_rn(__fadd_rn(un, u01(rbits(k_ru, li))), 64.0f);
  float rv = __fdiv_rn(__fadd_rn(vn, u01(rbits(k_rv, li))), 8.0f);
  float phi = __fmul_rn(ru, (float)(2.0 * M_PI));
  float ct  = __fadd_rn(__fmul_rn(rv, omc), mc);
  float stq = sqrtf(fmaxf(__fsub_rn(1.0f, __fmul_rn(ct, ct)), 0.0f));
  float dc0 = __fmul_rn(stq, cosf(phi));
  float dc1 = __fmul_rn(stq, sinf(phi));
  const float* Rv = dec + DEC_RT + v * 12;
  float o0 = Rv[3], o1 = Rv[7], o2 = Rv[11];
  float d0 = dc0 * Rv[0] + dc1 * Rv[1] + ct * Rv[2];
  float d1 = dc0 * Rv[4] + dc1 * Rv[5] + ct * Rv[6];
  float d2 = dc0 * Rv[8] + dc1 * Rv[9] + ct * Rv[10];

  // step positions (exact)
  for (int p = lane; p < NCS; p += 64) {
    float sp;
    if (p == 256) sp = __fmul_rn(0.015f, 128.0f);
    else {
      int b = p >> 1;
      float eb = __fmul_rn(0.015f, (float)b);
      if (p & 1) {
        float u = u01(rbits(k_eta, li * 128u + (uint32_t)b));
        sp = __fadd_rn(eb, __fmul_rn(u, 0.015f));
      } else sp = eb;
    }
    ss[p] = sp;
  }
  __syncthreads();

  // prepass: inside flags per interval (exact mid ops, same as alpha pass)
  for (int p = lane; p < 256; p += 64) {
    float s0 = ss[p], s1 = ss[p + 1];
    float ax = __fadd_rn(o0, __fmul_rn(s0, d0)), bx = __fadd_rn(o0, __fmul_rn(s1, d0));
    float ay = __fadd_rn(o1, __fmul_rn(s0, d1)), by = __fadd_rn(o1, __fmul_rn(s1, d1));
    float az = __fadd_rn(o2, __fmul_rn(s0, d2)), bz = __fadd_rn(o2, __fmul_rn(s1, d2));
    float mx = __fmul_rn(0.5f, __fadd_rn(ax, bx));
    float my = __fmul_rn(0.5f, __fadd_rn(ay, by));
    float mz = __fmul_rn(0.5f, __fadd_rn(az, bz));
    float n2 = __fadd_rn(__fadd_rn(__fmul_rn(mx, mx), __fmul_rn(my, my)), __fmul_rn(mz, mz));
    bool ins = (sqrtf(n2) < 1.0f) && (mz > 0.0f);
    sflagf[p] = ins ? 1.0f : 0.0f;
  }
  __syncthreads();

  // point-need flags + compaction (point p needed by intervals p-1,p,p+1)
  int cnt = 0;
  for (int c = 0; c < 5; c++) {
    int p = c * 64 + lane;
    bool need = false;
    if (p < NCS) {
      ssdf[p] = 0.0f;
      bool f0 = (p >= 1 && p - 1 < 256) ? (sflagf[p - 1] != 0.0f) : false;
      bool f1 = (p < 256) ? (sflagf[p] != 0.0f) : false;
      bool f2 = (p + 1 < 256) ? (sflagf[p + 1] != 0.0f) : false;
      need = f0 || f1 || f2;
    }
    unsigned long long m = __ballot(need);
    int idx = cnt + __popcll(m & ((1ull << lane) - 1ull));
    if (need) slist[idx] = p;
    cnt += __popcll(m);
  }
  __syncthreads();

  // MLP only for needed points — EXACT libm ops, same order as before
  for (int k = lane; k < cnt; k += 64) {
    int p = slist[k];
    float sp = ss[p];
    float px = __fadd_rn(o0, __fmul_rn(sp, d0));
    float py = __fadd_rn(o1, __fmul_rn(sp, d1));
    float pz = __fadd_rn(o2, __fmul_rn(sp, d2));
    float acc = 0.0f;
    for (int j = 0; j < HID; j++) {
      float t = fmaf(px, sW[j], fmaf(py, sW[64 + j], fmaf(pz, sW[128 + j], sW[192 + j])));
      acc = fmaf(softplusf_(t), sW[256 + j], acc);
    }
    ssdf[p] = __fadd_rn(acc, b2);
  }
  __syncthreads();

  // alpha per interval (exact; uses precomputed flags)
  for (int p = lane; p < 256; p += 64) {
    float s0 = ss[p], s1 = ss[p + 1];
    float f0 = ssdf[p], f1 = ssdf[p + 1];
    float delta = __fsub_rn(s1, s0);
    float mid_sdf = __fmul_rn(0.5f, __fadd_rn(f1, f0));
    float cosv = __fdiv_rn(__fsub_rn(f1, f0), __fadd_rn(delta, 1e-6f));
    float pcos = 0.0f;
    if (p > 0)
      pcos = __fdiv_rn(__fsub_rn(f0, ssdf[p - 1]),
                       __fadd_rn(__fsub_rn(s0, ss[p - 1]), 1e-6f));
    float cc = fminf(fmaxf(fminf(pcos, cosv), -1000.0f), 0.0f);
    float dsdf = __fmul_rn(__fmul_rn(0.5f, cc), delta);
    float pT = sigmoidf_(__fmul_rn(64.0f, __fsub_rn(mid_sdf, dsdf)));
    float nT = sigmoidf_(__fmul_rn(64.0f, __fadd_rn(mid_sdf, dsdf)));
    salpha[p] = __fmul_rn(__fsub_rn(1.0f, __fdiv_rn(nT, __fadd_rn(pT, 1e-6f))),
                          sflagf[p]);
  }
  __syncthreads();

  // serial pdf chain (exact, feeds categorical samplers — do not touch)
  if (lane == 0) {
    float T = 1.0f, rsum = 0.0f;
    int base = (v * NS + r) * NB;
    for (int b = 0; b < NB; b++) {
      float a0 = salpha[2 * b], a1 = salpha[2 * b + 1];
      float w0 = __fmul_rn(a0, T);
      float om = __fsub_rn(1.0f, a0);
      T = __fmul_rn(T, __fadd_rn(__fmul_rn(om, om), 1e-6f));
      float w1 = __fmul_rn(a1, T);
      om = __fsub_rn(1.0f, a1);
      T = __fmul_rn(T, __fadd_rn(__fmul_rn(om, om), 1e-6f));
      float spdf = __fadd_rn(w0, w1);
      c_step_pdf[base + b] = spdf;
      out[O_SPDF + base + b] = spdf;
      rsum = __fadd_rn(rsum, spdf);
    }
    c_ray_pdf[v * NS + r] = rsum;
    out[O_RPDF + v * NS + r] = rsum;
  }
}

// one 64-lane block per (p, v): argmax over 512 (gumbel + log(pdf+1e-6))
__global__ void __launch_bounds__(64) k_raycat(
    const float* __restrict__ c_ray_pdf, uint2 kg,
    int* __restrict__ f_idx, int* __restrict__ cnts) {
  int p = blockIdx.x, v = blockIdx.y, lane = threadIdx.x;
  uint32_t rowbase = ((uint32_t)p * 32u + (uint32_t)v) * 512u;
  float best = -INFINITY; int bi = 0;
  for (int n = lane; n < 512; n += 64) {
    float lg = logf(__fadd_rn(c_ray_pdf[v * 512 + n], 1e-6f));
    float val = __fadd_rn(gumbelf(rbits(kg, rowbase + (uint32_t)n)), lg);
    if (val > best) { best = val; bi = n; }
  }
  argmax_reduce64(best, bi);
  if (lane == 0) {
    f_idx[v * 64 + p] = bi;
    atomicAdd(&cnts[v * 512 + bi], 1);
  }
}

// one 64-lane block per (r, v); loop over the 32 pdf-step draws in-block
__global__ void __launch_bounds__(64) k_stepcat(
    const float* __restrict__ c_step_pdf, const int* __restrict__ f_idx,
    uint2 kg, int* __restrict__ bidx) {
  int r = blockIdx.x, v = blockIdx.y, lane = threadIdx.x;
  int n = (r < 512) ? r : f_idx[v * 64 + (r - 512)];
  const float* pdfrow = c_step_pdf + (v * 512 + n) * 128;
  float lg0 = logf(__fadd_rn(pdfrow[lane], 1e-6f));
  float lg1 = logf(__fadd_rn(pdfrow[64 + lane], 1e-6f));
  for (int p = 0; p < 32; p++) {
    uint32_t base = (((uint32_t)p * 32u + (uint32_t)v) * 576u + (uint32_t)r) * 128u;
    float v0 = __fadd_rn(gumbelf(rbits(kg, base + (uint32_t)lane)), lg0);
    float v1 = __fadd_rn(gumbelf(rbits(kg, base + 64u + (uint32_t)lane)), lg1);
    float best = v0; int bi = lane;
    if (v1 > best) { best = v1; bi = 64 + lane; }
    argmax_reduce64(best, bi);
    if (lane == 0) bidx[(v * 576 + r) * 32 + p] = bi;
  }
}

// one 64-lane block per fine ray — parallel merge/compaction/scan, fast MLP
__global__ void __launch_bounds__(64) k_fine(
    const float* __restrict__ dec, const int* __restrict__ f_idx,
    const int* __restrict__ cnts, const int* __restrict__ bidx,
    uint2 k_ru, uint2 k_rv, uint2 k_rup, uint2 k_rvp, uint2 k_eta, uint2 k_us,
    float mc, float omc, float sa,
    float* __restrict__ rad_rows, float* __restrict__ out) {
  int r = blockIdx.x, v = blockIdx.y, lane = threadIdx.x;
  __shared__ float sW[320];
  __shared__ float sb[NCS], pe[NPS], st[NFS];
  __shared__ float sal[NFM], sac[NFM], sT[NFM];
  __shared__ int   slist[NFM];
  __shared__ float bina[NB], binw[NB], binr[NB];
  for (int i = lane; i < 320; i += 64) sW[i] = dec[DEC_W1 + i];
  bina[lane] = 0.0f; binw[lane] = 0.0f; binr[lane] = 0.0f;
  bina[64 + lane] = 0.0f; binw[64 + lane] = 0.0f; binr[64 + lane] = 0.0f;
  float b2 = dec[DEC_B2], inv_s = dec[DEC_INVS], rho = dec[DEC_RHO];

  // ray setup (exact; positions feed geometry)
  int n; float ruB, rvB;
  if (r < 512) {
    n = r;
    ruB = u01(rbits(k_ru, (uint32_t)(v * 512 + r)));
    rvB = u01(rbits(k_rv, (uint32_t)(v * 512 + r)));
  } else {
    int p = r - 512;
    n = f_idx[v * 64 + p];
    ruB = u01(rbits(k_rup, (uint32_t)(v * 64 + p)));
    rvB = u01(rbits(k_rvp, (uint32_t)(v * 64 + p)));
  }
  float un = (float)(n >> 3), vn = (float)(n & 7);
  float ru = __fdiv_rn(__fadd_rn(un, ruB), 64.0f);
  float rv = __fdiv_rn(__fadd_rn(vn, rvB), 8.0f);
  float phi = __fmul_rn(ru, (float)(2.0 * M_PI));
  float ct  = __fadd_rn(__fmul_rn(rv, omc), mc);
  float stq = sqrtf(fmaxf(__fsub_rn(1.0f, __fmul_rn(ct, ct)), 0.0f));
  float dc0 = __fmul_rn(stq, cosf(phi));
  float dc1 = __fmul_rn(stq, sinf(phi));
  const float* Rv = dec + DEC_RT + v * 12;
  float o0 = Rv[3], o1 = Rv[7], o2 = Rv[11];
  float d0 = dc0 * Rv[0] + dc1 * Rv[1] + ct * Rv[2];
  float d1 = dc0 * Rv[4] + dc1 * Rv[5] + ct * Rv[6];
  float d2 = dc0 * Rv[8] + dc1 * Rv[9] + ct * Rv[10];
  float wb = __fdiv_rn(1.0f, __fmul_rn(__fadd_rn((float)cnts[v * 512 + n], 1.0f), 512.0f));
  float wray = __fmul_rn(__fmul_rn(wb, ct), sa);

  // base steps (exact RNG)
  uint32_t li = (uint32_t)(v * 576 + r);
  for (int p = lane; p < NCS; p += 64) {
    float sp;
    if (p == 256) sp = __fmul_rn(0.015f, 128.0f);
    else {
      int b = p >> 1;
      float eb = __fmul_rn(0.015f, (float)b);
      if (p & 1) {
        float u = u01(rbits(k_eta, li * 128u + (uint32_t)b));
        sp = __fadd_rn(eb, __fmul_rn(u, 0.015f));
      } else sp = eb;
    }
    sb[p] = sp;
  }
  if (lane < NPS) {
    int b = bidx[(v * 576 + r) * 32 + lane];
    float le = __fmul_rn(0.015f, (float)b);
    float u = u01(rbits(k_us, li * 32u + (uint32_t)lane));
    pe[lane] = __fadd_rn(le, __fmul_rn(u, 0.015f));
  }
  __syncthreads();

  // parallel merge via position scatter (sb sorted; pe unsorted)
  for (int c = 0; c < 5; c++) {
    int p = c * 64 + lane;
    if (p < NCS) {
      float x = sb[p];
      int cntlt = 0;
      for (int j = 0; j < NPS; j++) cntlt += (pe[j] < x) ? 1 : 0;
      st[p + cntlt] = x;
    }
  }
  if (lane < NPS) {
    float x = pe[lane];
    int lo = 0, hi = NCS;                    // #{sb <= x} via binary search
    while (lo < hi) { int m = (lo + hi) >> 1; if (sb[m] <= x) lo = m + 1; else hi = m; }
    int rk = 0;                              // stable rank among pe
    for (int j = 0; j < NPS; j++) {
      float y = pe[j];
      rk += (y < x || (y == x && j < lane)) ? 1 : 0;
    }
    st[lo + rk] = x;
  }
  __syncthreads();

  // inside flags, defaults, zero-stores for outside, compaction
  size_t obase = (size_t)(v * 576 + r) * NFM;
  int cnt = 0;
  for (int c = 0; c < 5; c++) {
    int p = c * 64 + lane;
    bool f = false;
    if (p < NFM) {
      float s0 = st[p], s1 = st[p + 1];
      float mid = __fmul_rn(0.5f, __fadd_rn(s1, s0));
      float px = __fadd_rn(o0, __fmul_rn(mid, d0));
      float py = __fadd_rn(o1, __fmul_rn(mid, d1));
      float pz = __fadd_rn(o2, __fmul_rn(mid, d2));
      float n2 = __fadd_rn(__fadd_rn(__fmul_rn(px, px), __fmul_rn(py, py)), __fmul_rn(pz, pz));
      f = (sqrtf(n2) < 1.0f) && (pz > 0.0f);
      sal[p] = 0.0f; sac[p] = 0.0f;
      if (!f) {
        out[O_SDF + obase + p] = 0.0f;
        out[O_ALPHA + obase + p] = 0.0f;
        size_t nb3 = (obase + p) * 3;
        out[O_NORMAL + nb3] = 0.0f;
        out[O_NORMAL + nb3 + 1] = 0.0f;
        out[O_NORMAL + nb3 + 2] = 0.0f;
      }
    }
    unsigned long long m = __ballot(f);
    int idx = cnt + __popcll(m & ((1ull << lane) - 1ull));
    if (f) slist[idx] = p;
    cnt += __popcll(m);
  }
  __syncthreads();

  // fast-math MLP + grad for inside points only
  for (int k = lane; k < cnt; k += 64) {
    int p = slist[k];
    float s0 = st[p], s1 = st[p + 1];
    float delta = s1 - s0;
    float mid = 0.5f * (s1 + s0);
    float px = fmaf(mid, d0, o0);
    float py = fmaf(mid, d1, o1);
    float pz = fmaf(mid, d2, o2);
    float acc = 0.0f, g0 = 0.0f, g1 = 0.0f, g2 = 0.0f;
    for (int j = 0; j < HID; j++) {
      float t = fmaf(px, sW[j], fmaf(py, sW[64 + j], fmaf(pz, sW[128 + j], sW[192 + j])));
      float e = __expf(-fabsf(t));
      float w2j = sW[256 + j];
      acc = fmaf(fmaxf(t, 0.0f) + __logf(1.0f + e), w2j, acc);
      float rr = frcp_(1.0f + e);
      float sg = (t >= 0.0f) ? rr : e * rr;
      float m = sg * w2j;
      g0 = fmaf(m, sW[j], g0);
      g1 = fmaf(m, sW[64 + j], g1);
      g2 = fmaf(m, sW[128 + j], g2);
    }
    float sdf = acc + b2;
    float cosr = fmaf(d0, g0, fmaf(d1, g1, d2 * g2));
    float ac = -fmaxf(fmaf(-cosr, 0.5f, 0.5f), 0.0f);
    float dsdf = 0.5f * ac * delta;
    float pT = fsig_(inv_s * (sdf - dsdf));
    float nT = fsig_(inv_s * (sdf + dsdf));
    float alpha = 1.0f - nT * frcp_(pT + 1e-6f);
    sal[p] = alpha; sac[p] = ac;
    out[O_SDF + obase + p] = sdf;
    size_t nb3 = (obase + p) * 3;
    out[O_NORMAL + nb3]     = g0;
    out[O_NORMAL + nb3 + 1] = g1;
    out[O_NORMAL + nb3 + 2] = g2;
    out[O_ALPHA + obase + p] = alpha;
  }
  __syncthreads();

  // parallel prefix-product T-scan over 288 (chunk 5 per lane + wave scan)
  {
    int q0 = lane * 5, q1 = q0 + 5 > NFM ? NFM : q0 + 5;
    float lp = 1.0f;
    for (int q = q0; q < q1; q++) { float om = 1.0f - sal[q]; lp *= om * om; }
    float x = lp;
    for (int d = 1; d < 64; d <<= 1) {
      float y = __shfl_up(x, d);
      if (lane >= d) x *= y;
    }
    float excl = __shfl_up(x, 1);
    if (lane == 0) excl = 1.0f;
    float T = excl;
    for (int q = q0; q < q1; q++) {
      sT[q] = T;
      float om = 1.0f - sal[q];
      T *= om * om;
    }
  }
  __syncthreads();

  // outputs + LDS-atomic binning (parallel over p)
  for (int c = 0; c < 5; c++) {
    int p = c * 64 + lane;
    if (p < NFM) {
      float T = sT[p], a = sal[p];
      float wgt = a * T;
      out[O_T + obase + p] = T;
      out[O_W + obase + p] = wgt;
      float s0 = st[p], s1 = st[p + 1];
      float mid = __fmul_rn(0.5f, __fadd_rn(s1, s0));
      int bi = (int)floorf(__fdiv_rn(mid, 0.015f));
      bi = bi < 0 ? 0 : (bi > 127 ? 127 : bi);
      bool valid = (mid > __fmul_rn((float)bi, 0.015f)) &&
                   (mid < __fmul_rn((float)(bi + 1), 0.015f));
      if (valid) {
        atomicAdd(&bina[bi], a);
        atomicAdd(&binw[bi], wgt);
        float inner = (-sac[p]) * frcp_(fmaf(mid, mid, 1e-6f));
        atomicAdd(&binr[bi], wgt * rho * inner);
      }
    }
  }
  __syncthreads();

  size_t bb = (size_t)(v * 576 + r) * NB;
  for (int c = 0; c < 2; c++) {
    int b = c * 64 + lane;
    out[O_BA + bb + b] = bina[b];
    out[O_BW + bb + b] = binw[b];
    rad_rows[bb + b] = __fmul_rn(binr[b], wray);
  }
  float opv = binw[lane] + binw[64 + lane];
  for (int d = 32; d; d >>= 1) opv += __shfl_xor(opv, d);
  if (lane == 0) out[O_OP + (size_t)(v * 576 + r)] = opv;
}

// gather hists[v,b] = sum over 576 rays of rad_rows
__global__ void k_final(const float* __restrict__ rad_rows,
                        float* __restrict__ out) {
  int i = blockIdx.x * 256 + threadIdx.x;
  if (i < 4096) {
    int v = i >> 7, b = i & 127;
    const float* base = rad_rows + (size_t)v * 576 * 128 + b;
    float s = 0.0f;
    for (int r = 0; r < 576; r++) s = __fadd_rn(s, base[(size_t)r * 128]);
    out[O_HISTS + i] = s;
  }
}

// ======================= launch ===========================================
extern "C" void kernel_launch(void* const* d_in, const int* in_sizes, int n_in,
                              void* d_out, int out_size, void* d_ws, size_t ws_size,
                              hipStream_t stream) {
  float* out = (float*)d_out;

  const size_t WS_NEED = 5081856u * 4u;
  if (n_in != 7) { hipMemsetAsync(d_out, 0x75, 4, stream); return; }
  static const int want[7] = {384, 192, 64, 64, 1, 1, 1};
  for (int i = 0; i < 7; i++)
    if (in_sizes[i] != want[i]) { hipMemsetAsync(d_out, 0x74, 4, stream); return; }
  if (ws_size < WS_NEED) { hipMemsetAsync(d_out, 0x77, 4, stream); return; }
  (void)out_size;

  uint32_t root[2] = {0u, 42u};
  uint32_t kcf[2][2]; jax_split(root, 2, kcf);
  uint32_t ck[2][2];  jax_split(kcf[0], 2, ck);
  uint32_t crk[5][2]; jax_split(ck[0], 5, crk);
  uint32_t csk[3][2]; jax_split(ck[1], 3, csk);
  uint32_t fk2[2][2]; jax_split(kcf[1], 2, fk2);
  uint32_t frk[5][2]; jax_split(fk2[0], 5, frk);
  uint32_t fsk[3][2]; jax_split(fk2[1], 3, fsk);

  float mc  = (float)cos(60.0 * M_PI / 360.0);
  float omc = 1.0f - mc;
  float sa  = (float)(2.0 * M_PI * (1.0 - (double)mc));

  float* ws = (float*)d_ws;
  size_t off = 0;
  float* dec        = ws + off; off += 768;
  float* c_step_pdf = ws + off; off += 2097152;
  float* c_ray_pdf  = ws + off; off += 16384;
  int*   f_idx      = (int*)(ws + off); off += 2048;
  int*   cnts       = (int*)(ws + off); off += 16384;
  int*   bidx       = (int*)(ws + off); off += 589824;
  float* rad_rows   = ws + off; off += 2359296;

  k_decode<<<1, 256, 0, stream>>>(d_in[0], d_in[1], d_in[2], d_in[3],
                                  d_in[4], d_in[5], d_in[6], dec);
  k_zero<<<64, 256, 0, stream>>>(cnts);
  k_coarse<<<dim3(512, 32), 64, 0, stream>>>(dec,
      mkk(crk[0]), mkk(crk[1]), mkk(csk[0]), mc, omc, c_step_pdf, c_ray_pdf, out);
  k_raycat<<<dim3(64, 32), 64, 0, stream>>>(c_ray_pdf, mkk(frk[2]), f_idx, cnts);
  k_stepcat<<<dim3(576, 32), 64, 0, stream>>>(c_step_pdf, f_idx, mkk(fsk[1]), bidx);
  k_fine<<<dim3(576, 32), 64, 0, stream>>>(dec, f_idx, cnts, bidx,
      mkk(frk[0]), mkk(frk[1]), mkk(frk[3]), mkk(frk[4]), mkk(fsk[0]), mkk(fsk[2]),
      mc, omc, sa, rad_rows, out);
  k_final<<<16, 256, 0, stream>>>(rad_rows, out);
}

// Round 7
// 813.684 us; speedup vs baseline: 7.9892x; 1.4738x over previous
//
#include <hip/hip_runtime.h>
#include <stdint.h>
#include <math.h>

// =====================================================================
// NeuS renderer — bit-faithful JAX threefry RNG (partitionable mode).
// R7: k_coarse two-tier MLP with EXACT interval guards:
//   fast approx pass classifies intervals; sigmoid saturation zones get
//   provably-exact constant alphas (any <=1ulp exp rounds identically);
//   exact libm MLP only for transition-band points. Guard margins:
//   |dsdf| <= 0.5*delta*min(1000,G), G = sum |w2_j|*||W1col_j|| (rigorous),
//   approx error budget 0.02 (~160x empirical). Coarse outputs bit-identical.
// Also: float4-packed weight LDS, parallel k_final.
// =====================================================================

#define NS    512
#define NB    128
#define NCS   257
#define NPS   32
#define NFS   289
#define NFM   288
#define HID   64

// output element offsets (fp32 elements), reference return order
#define O_HISTS  0
#define O_SDF    4096
#define O_NORMAL 5312512
#define O_ALPHA  21237760
#define O_T      26546176
#define O_W      31854592
#define O_BA     37163008
#define O_BW     39522304
#define O_OP     41881600
#define O_RPDF   41900032
#define O_SPDF   41916416

// dec[] layout (fp32 canonical inputs in ws)
#define DEC_RT   0
#define DEC_W1   384
#define DEC_B1   576
#define DEC_W2   640
#define DEC_B2   704
#define DEC_INVS 705
#define DEC_RHO  706
#define DEC_G    707

// ---------------- threefry2x32 -------------------------------------------
__host__ __device__ inline void tf2x32(uint32_t k0, uint32_t k1,
                                       uint32_t x0, uint32_t x1,
                                       uint32_t& o0, uint32_t& o1) {
  uint32_t ks2 = k0 ^ k1 ^ 0x1BD11BDAu;
  x0 += k0; x1 += k1;
#define TFR(r) { x0 += x1; x1 = (x1 << (r)) | (x1 >> (32 - (r))); x1 ^= x0; }
  TFR(13) TFR(15) TFR(26) TFR(6)
  x0 += k1;  x1 += ks2 + 1u;
  TFR(17) TFR(29) TFR(16) TFR(24)
  x0 += ks2; x1 += k0 + 2u;
  TFR(13) TFR(15) TFR(26) TFR(6)
  x0 += k0;  x1 += k1 + 3u;
  TFR(17) TFR(29) TFR(16) TFR(24)
  x0 += k1;  x1 += ks2 + 4u;
  TFR(13) TFR(15) TFR(26) TFR(6)
  x0 += ks2; x1 += k0 + 5u;
#undef TFR
  o0 = x0; o1 = x1;
}

__device__ inline uint32_t rbits(uint2 k, uint32_t i) {
  uint32_t a, b; tf2x32(k.x, k.y, 0u, i, a, b);
  return a ^ b;
}

__device__ inline float u01(uint32_t bits) {
  return __uint_as_float(0x3f800000u | (bits >> 9)) - 1.0f;
}
__device__ inline float gumbelf(uint32_t bits) {
  float f = u01(bits);
  float u = (f > 0.0f) ? f : 1.17549435082228751e-38f;
  return -logf(-logf(u));
}
__device__ inline float sigmoidf_(float x) {           // libm-exact
  return __fdiv_rn(1.0f, __fadd_rn(1.0f, expf(-x)));
}
__device__ inline float softplusf_(float x) {          // libm-exact
  return __fadd_rn(fmaxf(x, 0.0f), log1pf(expf(-fabsf(x))));
}
__device__ inline float frcp_(float x) { return __builtin_amdgcn_rcpf(x); }
__device__ inline float fsig_(float x) { return frcp_(1.0f + __expf(-x)); }
__device__ inline void argmax_reduce64(float& best, int& bi) {
  for (int off = 1; off < 64; off <<= 1) {
    float ob = __shfl_xor(best, off);
    int   oi = __shfl_xor(bi, off);
    if (ob > best || (ob == best && oi < bi)) { best = ob; bi = oi; }
  }
}

// ---------------- host key derivation (jax.random.split) ------------------
static void jax_split(const uint32_t k[2], int n, uint32_t out[][2]) {
  for (int j = 0; j < n; j++)
    tf2x32(k[0], k[1], 0u, (uint32_t)j, out[j][0], out[j][1]);
}
static inline uint2 mkk(const uint32_t k[2]) { return make_uint2(k[0], k[1]); }

// ======================= kernels ==========================================
__device__ inline float ld_as(const void* p, int i, int isbf) {
  if (isbf) {
    uint16_t h = ((const uint16_t*)p)[i];
    return __uint_as_float(((uint32_t)h) << 16);
  }
  return ((const float*)p)[i];
}

__global__ void k_decode(const void* Rt, const void* W1, const void* b1,
                         const void* w2, const void* b2, const void* invs,
                         const void* rho, float* dec) {
  __shared__ int sflag;
  if (threadIdx.x == 0) {
    float errF = 0.0f, errB = 0.0f;
    for (int v = 0; v < 8; v++)
      for (int row = 0; row < 3; row++) {
        float nF = 0.0f, nB = 0.0f;
        for (int j = 0; j < 3; j++) {
          float aF = ld_as(Rt, v * 12 + row * 4 + j, 0); nF += aF * aF;
          float aB = ld_as(Rt, v * 12 + row * 4 + j, 1); nB += aB * aB;
        }
        errF += fabsf(nF - 1.0f); errB += fabsf(nB - 1.0f);
      }
    int pickF = (errF == errF) && (!(errB == errB) || errF < errB);
    sflag = pickF ? 0 : 1;
  }
  __syncthreads();
  int f = sflag, t = threadIdx.x;
  for (int i = t; i < 384; i += 256) dec[DEC_RT + i] = ld_as(Rt, i, f);
  if (t < 192) dec[DEC_W1 + t] = ld_as(W1, t, f);
  if (t < 64)  dec[DEC_B1 + t] = ld_as(b1, t, f);
  if (t < 64)  dec[DEC_W2 + t] = ld_as(w2, t, f);
  if (t == 0) {
    dec[DEC_B2]   = ld_as(b2, 0, f);
    dec[DEC_INVS] = ld_as(invs, 0, f);
    dec[DEC_RHO]  = ld_as(rho, 0, f);
    float G = 0.0f;                        // rigorous |directional grad| bound
    for (int j = 0; j < 64; j++) {
      float wx = ld_as(W1, j, f), wy = ld_as(W1, 64 + j, f), wz = ld_as(W1, 128 + j, f);
      G += fabsf(ld_as(w2, j, f)) * sqrtf(wx * wx + wy * wy + wz * wz);
    }
    dec[DEC_G] = G * 1.02f + 0.001f;       // slop for fp rounding
  }
}

__global__ void k_zero(int* __restrict__ cnts) {
  int i = blockIdx.x * 256 + threadIdx.x;
  if (i < 16384) cnts[i] = 0;
}

// one 64-lane block per coarse ray — two-tier MLP, bit-exact outputs
__global__ void __launch_bounds__(64) k_coarse(
    const float* __restrict__ dec,
    uint2 k_ru, uint2 k_rv, uint2 k_eta, float mc, float omc,
    float* __restrict__ c_step_pdf, float* __restrict__ c_ray_pdf,
    float* __restrict__ out) {
  int r = blockIdx.x, v = blockIdx.y, lane = threadIdx.x;
  __shared__ float4 sW4[64];               // {w1x, w1y, w1z, b1}
  __shared__ float  sw2[64];
  __shared__ float ss[NCS], sfa[NCS], sfe[NCS], salpha[256], sflagf[256];
  __shared__ int   slist[NCS], scls[256];
  if (lane < 64) {
    sW4[lane] = make_float4(dec[DEC_W1 + lane], dec[DEC_W1 + 64 + lane],
                            dec[DEC_W1 + 128 + lane], dec[DEC_B1 + lane]);
    sw2[lane] = dec[DEC_W2 + lane];
  }
  float b2 = dec[DEC_B2];
  float G  = dec[DEC_G];
  float Gm = fminf(1000.0f, G);
  // exact saturated-alpha constant: same ops the reference performs
  float alpha_c = __fsub_rn(1.0f, __fdiv_rn(1.0f, __fadd_rn(1.0f, 1e-6f)));

  uint32_t li = (uint32_t)(v * NS + r);
  float un = (float)(r >> 3), vn = (float)(r & 7);
  float ru = __fdiv_rn(__fadd_rn(un, u01(rbits(k_ru, li))), 64.0f);
  float rv = __fdiv_rn(__fadd_rn(vn, u01(rbits(k_rv, li))), 8.0f);
  float phi = __fmul_rn(ru, (float)(2.0 * M_PI));
  float ct  = __fadd_rn(__fmul_rn(rv, omc), mc);
  float stq = sqrtf(fmaxf(__fsub_rn(1.0f, __fmul_rn(ct, ct)), 0.0f));
  float dc0 = __fmul_rn(stq, cosf(phi));
  float dc1 = __fmul_rn(stq, sinf(phi));
  const float* Rv = dec + DEC_RT + v * 12;
  float o0 = Rv[3], o1 = Rv[7], o2 = Rv[11];
  float d0 = dc0 * Rv[0] + dc1 * Rv[1] + ct * Rv[2];
  float d1 = dc0 * Rv[4] + dc1 * Rv[5] + ct * Rv[6];
  float d2 = dc0 * Rv[8] + dc1 * Rv[9] + ct * Rv[10];

  // step positions (exact RNG)
  for (int p = lane; p < NCS; p += 64) {
    float sp;
    if (p == 256) sp = __fmul_rn(0.015f, 128.0f);
    else {
      int b = p >> 1;
      float eb = __fmul_rn(0.015f, (float)b);
      if (p & 1) {
        float u = u01(rbits(k_eta, li * 128u + (uint32_t)b));
        sp = __fadd_rn(eb, __fmul_rn(u, 0.015f));
      } else sp = eb;
    }
    ss[p] = sp;
  }
  __syncthreads();

  // inside flags per interval (exact ops — same values the ref computes)
  for (int p = lane; p < 256; p += 64) {
    float s0 = ss[p], s1 = ss[p + 1];
    float ax = __fadd_rn(o0, __fmul_rn(s0, d0)), bx = __fadd_rn(o0, __fmul_rn(s1, d0));
    float ay = __fadd_rn(o1, __fmul_rn(s0, d1)), by = __fadd_rn(o1, __fmul_rn(s1, d1));
    float az = __fadd_rn(o2, __fmul_rn(s0, d2)), bz = __fadd_rn(o2, __fmul_rn(s1, d2));
    float mx = __fmul_rn(0.5f, __fadd_rn(ax, bx));
    float my = __fmul_rn(0.5f, __fadd_rn(ay, by));
    float mz = __fmul_rn(0.5f, __fadd_rn(az, bz));
    float n2 = __fadd_rn(__fadd_rn(__fmul_rn(mx, mx), __fmul_rn(my, my)), __fmul_rn(mz, mz));
    bool ins = (sqrtf(n2) < 1.0f) && (mz > 0.0f);
    sflagf[p] = ins ? 1.0f : 0.0f;
  }
  __syncthreads();

  // needed points (inside-adjacent) -> compaction
  int ncnt = 0;
  for (int c = 0; c < 5; c++) {
    int p = c * 64 + lane;
    bool need = false;
    if (p < NCS) {
      bool f0 = (p >= 1) ? (sflagf[p - 1] != 0.0f) : false;
      bool f1 = (p < 256) ? (sflagf[p] != 0.0f) : false;
      bool f2 = (p + 1 < 256) ? (sflagf[p + 1] != 0.0f) : false;
      need = f0 || f1 || f2;
    }
    unsigned long long m = __ballot(need);
    int idx = ncnt + __popcll(m & ((1ull << lane) - 1ull));
    if (need) slist[idx] = p;
    ncnt += __popcll(m);
  }
  __syncthreads();

  // TIER 1: fast approx sdf for needed points (classification only)
  for (int k = lane; k < ncnt; k += 64) {
    int p = slist[k];
    float sp = ss[p];
    float px = fmaf(sp, d0, o0);
    float py = fmaf(sp, d1, o1);
    float pz = fmaf(sp, d2, o2);
    float acc = 0.0f;
    for (int j = 0; j < HID; j++) {
      float4 q = sW4[j];
      float t = fmaf(px, q.x, fmaf(py, q.y, fmaf(pz, q.z, q.w)));
      float e = __expf(-fabsf(t));
      acc = fmaf(fmaxf(t, 0.0f) + __logf(1.0f + e), sw2[j], acc);
    }
    sfa[p] = acc + b2;
  }
  __syncthreads();

  // classify intervals: 0=outside, 1=SAT+ (alpha=alpha_c), 2=SAT- (alpha=1),
  // 3=BAND (needs exact sdf). Margins: EPS=0.02 approx err, Bd dsdf bound.
  for (int p = lane; p < 256; p += 64) {
    int cls = 0;
    if (sflagf[p] != 0.0f) {
      float delta = __fsub_rn(ss[p + 1], ss[p]);
      float Bd = 0.5f * delta * Gm * 1.01f + 1e-6f;
      float ma = 0.5f * (sfa[p] + sfa[p + 1]);
      float margin = Bd + 0.02f;
      if (ma - margin > 0.28f)       cls = 1;   // both sigmoids round to 1.0f
      else if (ma + margin < -0.52f) cls = 2;   // pT+1e-6==1e-6f, alpha==1.0f
      else                            cls = 3;
    }
    scls[p] = cls;
  }
  __syncthreads();

  // exact points: dilation of BAND intervals
  int ecnt = 0;
  for (int c = 0; c < 5; c++) {
    int p = c * 64 + lane;
    bool need = false;
    if (p < NCS) {
      bool f0 = (p >= 1) ? (scls[p - 1] == 3) : false;
      bool f1 = (p < 256) ? (scls[p] == 3) : false;
      bool f2 = (p + 1 < 256) ? (scls[p + 1] == 3) : false;
      need = f0 || f1 || f2;
    }
    unsigned long long m = __ballot(need);
    int idx = ecnt + __popcll(m & ((1ull << lane) - 1ull));
    if (need) slist[idx] = p;
    ecnt += __popcll(m);
  }
  __syncthreads();

  // TIER 2: EXACT libm MLP (identical op sequence to verified R4-R6)
  for (int k = lane; k < ecnt; k += 64) {
    int p = slist[k];
    float sp = ss[p];
    float px = __fadd_rn(o0, __fmul_rn(sp, d0));
    float py = __fadd_rn(o1, __fmul_rn(sp, d1));
    float pz = __fadd_rn(o2, __fmul_rn(sp, d2));
    float acc = 0.0f;
    for (int j = 0; j < HID; j++) {
      float4 q = sW4[j];
      float t = fmaf(px, q.x, fmaf(py, q.y, fmaf(pz, q.z, q.w)));
      acc = fmaf(softplusf_(t), sw2[j], acc);
    }
    sfe[p] = __fadd_rn(acc, b2);
  }
  __syncthreads();

  // alpha per interval
  for (int p = lane; p < 256; p += 64) {
    int cls = scls[p];
    float a;
    if (cls == 0)      a = 0.0f;
    else if (cls == 1) a = alpha_c;
    else if (cls == 2) a = 1.0f;
    else {
      float s0 = ss[p], s1 = ss[p + 1];
      float f0 = sfe[p], f1 = sfe[p + 1];
      float delta = __fsub_rn(s1, s0);
      float mid_sdf = __fmul_rn(0.5f, __fadd_rn(f1, f0));
      float cosv = __fdiv_rn(__fsub_rn(f1, f0), __fadd_rn(delta, 1e-6f));
      float pcos = 0.0f;
      if (p > 0)
        pcos = __fdiv_rn(__fsub_rn(f0, sfe[p - 1]),
                         __fadd_rn(__fsub_rn(s0, ss[p - 1]), 1e-6f));
      float cc = fminf(fmaxf(fminf(pcos, cosv), -1000.0f), 0.0f);
      float dsdf = __fmul_rn(__fmul_rn(0.5f, cc), delta);
      float pT = sigmoidf_(__fmul_rn(64.0f, __fsub_rn(mid_sdf, dsdf)));
      float nT = sigmoidf_(__fmul_rn(64.0f, __fadd_rn(mid_sdf, dsdf)));
      a = __fmul_rn(__fsub_rn(1.0f, __fdiv_rn(nT, __fadd_rn(pT, 1e-6f))), 1.0f);
    }
    salpha[p] = a;
  }
  __syncthreads();

  // serial pdf chain (exact, unchanged — feeds categorical samplers)
  if (lane == 0) {
    float T = 1.0f, rsum = 0.0f;
    int base = (v * NS + r) * NB;
    for (int b = 0; b < NB; b++) {
      float a0 = salpha[2 * b], a1 = salpha[2 * b + 1];
      float w0 = __fmul_rn(a0, T);
      float om = __fsub_rn(1.0f, a0);
      T = __fmul_rn(T, __fadd_rn(__fmul_rn(om, om), 1e-6f));
      float w1 = __fmul_rn(a1, T);
      om = __fsub_rn(1.0f, a1);
      T = __fmul_rn(T, __fadd_rn(__fmul_rn(om, om), 1e-6f));
      float spdf = __fadd_rn(w0, w1);
      c_step_pdf[base + b] = spdf;
      out[O_SPDF + base + b] = spdf;
      rsum = __fadd_rn(rsum, spdf);
    }
    c_ray_pdf[v * NS + r] = rsum;
    out[O_RPDF + v * NS + r] = rsum;
  }
}

// one 64-lane block per (p, v): argmax over 512 (gumbel + log(pdf+1e-6))
__global__ void __launch_bounds__(64) k_raycat(
    const float* __restrict__ c_ray_pdf, uint2 kg,
    int* __restrict__ f_idx, int* __restrict__ cnts) {
  int p = blockIdx.x, v = blockIdx.y, lane = threadIdx.x;
  uint32_t rowbase = ((uint32_t)p * 32u + (uint32_t)v) * 512u;
  float best = -INFINITY; int bi = 0;
  for (int n = lane; n < 512; n += 64) {
    float lg = logf(__fadd_rn(c_ray_pdf[v * 512 + n], 1e-6f));
    float val = __fadd_rn(gumbelf(rbits(kg, rowbase + (uint32_t)n)), lg);
    if (val > best) { best = val; bi = n; }
  }
  argmax_reduce64(best, bi);
  if (lane == 0) {
    f_idx[v * 64 + p] = bi;
    atomicAdd(&cnts[v * 512 + bi], 1);
  }
}

// one 64-lane block per (r, v); loop over the 32 pdf-step draws in-block
__global__ void __launch_bounds__(64) k_stepcat(
    const float* __restrict__ c_step_pdf, const int* __restrict__ f_idx,
    uint2 kg, int* __restrict__ bidx) {
  int r = blockIdx.x, v = blockIdx.y, lane = threadIdx.x;
  int n = (r < 512) ? r : f_idx[v * 64 + (r - 512)];
  const float* pdfrow = c_step_pdf + (v * 512 + n) * 128;
  float lg0 = logf(__fadd_rn(pdfrow[lane], 1e-6f));
  float lg1 = logf(__fadd_rn(pdfrow[64 + lane], 1e-6f));
  for (int p = 0; p < 32; p++) {
    uint32_t base = (((uint32_t)p * 32u + (uint32_t)v) * 576u + (uint32_t)r) * 128u;
    float v0 = __fadd_rn(gumbelf(rbits(kg, base + (uint32_t)lane)), lg0);
    float v1 = __fadd_rn(gumbelf(rbits(kg, base + 64u + (uint32_t)lane)), lg1);
    float best = v0; int bi = lane;
    if (v1 > best) { best = v1; bi = 64 + lane; }
    argmax_reduce64(best, bi);
    if (lane == 0) bidx[(v * 576 + r) * 32 + p] = bi;
  }
}

// one 64-lane block per fine ray — parallel merge/compaction/scan, fast MLP
__global__ void __launch_bounds__(64) k_fine(
    const float* __restrict__ dec, const int* __restrict__ f_idx,
    const int* __restrict__ cnts, const int* __restrict__ bidx,
    uint2 k_ru, uint2 k_rv, uint2 k_rup, uint2 k_rvp, uint2 k_eta, uint2 k_us,
    float mc, float omc, float sa,
    float* __restrict__ rad_rows, float* __restrict__ out) {
  int r = blockIdx.x, v = blockIdx.y, lane = threadIdx.x;
  __shared__ float4 sW4[64];
  __shared__ float  sw2[64];
  __shared__ float sb[NCS], pe[NPS], st[NFS];
  __shared__ float sal[NFM], sac[NFM], sT[NFM];
  __shared__ int   slist[NFM];
  __shared__ float bina[NB], binw[NB], binr[NB];
  if (lane < 64) {
    sW4[lane] = make_float4(dec[DEC_W1 + lane], dec[DEC_W1 + 64 + lane],
                            dec[DEC_W1 + 128 + lane], dec[DEC_B1 + lane]);
    sw2[lane] = dec[DEC_W2 + lane];
  }
  bina[lane] = 0.0f; binw[lane] = 0.0f; binr[lane] = 0.0f;
  bina[64 + lane] = 0.0f; binw[64 + lane] = 0.0f; binr[64 + lane] = 0.0f;
  float b2 = dec[DEC_B2], inv_s = dec[DEC_INVS], rho = dec[DEC_RHO];

  int n; float ruB, rvB;
  if (r < 512) {
    n = r;
    ruB = u01(rbits(k_ru, (uint32_t)(v * 512 + r)));
    rvB = u01(rbits(k_rv, (uint32_t)(v * 512 + r)));
  } else {
    int p = r - 512;
    n = f_idx[v * 64 + p];
    ruB = u01(rbits(k_rup, (uint32_t)(v * 64 + p)));
    rvB = u01(rbits(k_rvp, (uint32_t)(v * 64 + p)));
  }
  float un = (float)(n >> 3), vn = (float)(n & 7);
  float ru = __fdiv_rn(__fadd_rn(un, ruB), 64.0f);
  float rv = __fdiv_rn(__fadd_rn(vn, rvB), 8.0f);
  float phi = __fmul_rn(ru, (float)(2.0 * M_PI));
  float ct  = __fadd_rn(__fmul_rn(rv, omc), mc);
  float stq = sqrtf(fmaxf(__fsub_rn(1.0f, __fmul_rn(ct, ct)), 0.0f));
  float dc0 = __fmul_rn(stq, cosf(phi));
  float dc1 = __fmul_rn(stq, sinf(phi));
  const float* Rv = dec + DEC_RT + v * 12;
  float o0 = Rv[3], o1 = Rv[7], o2 = Rv[11];
  float d0 = dc0 * Rv[0] + dc1 * Rv[1] + ct * Rv[2];
  float d1 = dc0 * Rv[4] + dc1 * Rv[5] + ct * Rv[6];
  float d2 = dc0 * Rv[8] + dc1 * Rv[9] + ct * Rv[10];
  float wb = __fdiv_rn(1.0f, __fmul_rn(__fadd_rn((float)cnts[v * 512 + n], 1.0f), 512.0f));
  float wray = __fmul_rn(__fmul_rn(wb, ct), sa);

  uint32_t li = (uint32_t)(v * 576 + r);
  for (int p = lane; p < NCS; p += 64) {
    float sp;
    if (p == 256) sp = __fmul_rn(0.015f, 128.0f);
    else {
      int b = p >> 1;
      float eb = __fmul_rn(0.015f, (float)b);
      if (p & 1) {
        float u = u01(rbits(k_eta, li * 128u + (uint32_t)b));
        sp = __fadd_rn(eb, __fmul_rn(u, 0.015f));
      } else sp = eb;
    }
    sb[p] = sp;
  }
  if (lane < NPS) {
    int b = bidx[(v * 576 + r) * 32 + lane];
    float le = __fmul_rn(0.015f, (float)b);
    float u = u01(rbits(k_us, li * 32u + (uint32_t)lane));
    pe[lane] = __fadd_rn(le, __fmul_rn(u, 0.015f));
  }
  __syncthreads();

  // parallel merge via position scatter
  for (int c = 0; c < 5; c++) {
    int p = c * 64 + lane;
    if (p < NCS) {
      float x = sb[p];
      int cntlt = 0;
      for (int j = 0; j < NPS; j++) cntlt += (pe[j] < x) ? 1 : 0;
      st[p + cntlt] = x;
    }
  }
  if (lane < NPS) {
    float x = pe[lane];
    int lo = 0, hi = NCS;
    while (lo < hi) { int m = (lo + hi) >> 1; if (sb[m] <= x) lo = m + 1; else hi = m; }
    int rk = 0;
    for (int j = 0; j < NPS; j++) {
      float y = pe[j];
      rk += (y < x || (y == x && j < lane)) ? 1 : 0;
    }
    st[lo + rk] = x;
  }
  __syncthreads();

  // inside flags, zero-stores for outside, compaction
  size_t obase = (size_t)(v * 576 + r) * NFM;
  int cnt = 0;
  for (int c = 0; c < 5; c++) {
    int p = c * 64 + lane;
    bool f = false;
    if (p < NFM) {
      float s0 = st[p], s1 = st[p + 1];
      float mid = __fmul_rn(0.5f, __fadd_rn(s1, s0));
      float px = __fadd_rn(o0, __fmul_rn(mid, d0));
      float py = __fadd_rn(o1, __fmul_rn(mid, d1));
      float pz = __fadd_rn(o2, __fmul_rn(mid, d2));
      float n2 = __fadd_rn(__fadd_rn(__fmul_rn(px, px), __fmul_rn(py, py)), __fmul_rn(pz, pz));
      f = (sqrtf(n2) < 1.0f) && (pz > 0.0f);
      sal[p] = 0.0f; sac[p] = 0.0f;
      if (!f) {
        out[O_SDF + obase + p] = 0.0f;
        out[O_ALPHA + obase + p] = 0.0f;
        size_t nb3 = (obase + p) * 3;
        out[O_NORMAL + nb3] = 0.0f;
        out[O_NORMAL + nb3 + 1] = 0.0f;
        out[O_NORMAL + nb3 + 2] = 0.0f;
      }
    }
    unsigned long long m = __ballot(f);
    int idx = cnt + __popcll(m & ((1ull << lane) - 1ull));
    if (f) slist[idx] = p;
    cnt += __popcll(m);
  }
  __syncthreads();

  // fast-math MLP + grad for inside points
  for (int k = lane; k < cnt; k += 64) {
    int p = slist[k];
    float s0 = st[p], s1 = st[p + 1];
    float delta = s1 - s0;
    float mid = 0.5f * (s1 + s0);
    float px = fmaf(mid, d0, o0);
    float py = fmaf(mid, d1, o1);
    float pz = fmaf(mid, d2, o2);
    float acc = 0.0f, g0 = 0.0f, g1 = 0.0f, g2 = 0.0f;
    for (int j = 0; j < HID; j++) {
      float4 q = sW4[j];
      float t = fmaf(px, q.x, fmaf(py, q.y, fmaf(pz, q.z, q.w)));
      float e = __expf(-fabsf(t));
      float w2j = sw2[j];
      acc = fmaf(fmaxf(t, 0.0f) + __logf(1.0f + e), w2j, acc);
      float rr = frcp_(1.0f + e);
      float sg = (t >= 0.0f) ? rr : e * rr;
      float m = sg * w2j;
      g0 = fmaf(m, q.x, g0);
      g1 = fmaf(m, q.y, g1);
      g2 = fmaf(m, q.z, g2);
    }
    float sdf = acc + b2;
    float cosr = fmaf(d0, g0, fmaf(d1, g1, d2 * g2));
    float ac = -fmaxf(fmaf(-cosr, 0.5f, 0.5f), 0.0f);
    float dsdf = 0.5f * ac * delta;
    float pT = fsig_(inv_s * (sdf - dsdf));
    float nT = fsig_(inv_s * (sdf + dsdf));
    float alpha = 1.0f - nT * frcp_(pT + 1e-6f);
    sal[p] = alpha; sac[p] = ac;
    out[O_SDF + obase + p] = sdf;
    size_t nb3 = (obase + p) * 3;
    out[O_NORMAL + nb3]     = g0;
    out[O_NORMAL + nb3 + 1] = g1;
    out[O_NORMAL + nb3 + 2] = g2;
    out[O_ALPHA + obase + p] = alpha;
  }
  __syncthreads();

  // parallel prefix-product T-scan over 288
  {
    int q0 = lane * 5, q1 = q0 + 5 > NFM ? NFM : q0 + 5;
    float lp = 1.0f;
    for (int q = q0; q < q1; q++) { float om = 1.0f - sal[q]; lp *= om * om; }
    float x = lp;
    for (int d = 1; d < 64; d <<= 1) {
      float y = __shfl_up(x, d);
      if (lane >= d) x *= y;
    }
    float excl = __shfl_up(x, 1);
    if (lane == 0) excl = 1.0f;
    float T = excl;
    for (int q = q0; q < q1; q++) {
      sT[q] = T;
      float om = 1.0f - sal[q];
      T *= om * om;
    }
  }
  __syncthreads();

  // outputs + LDS-atomic binning
  for (int c = 0; c < 5; c++) {
    int p = c * 64 + lane;
    if (p < NFM) {
      float T = sT[p], a = sal[p];
      float wgt = a * T;
      out[O_T + obase + p] = T;
      out[O_W + obase + p] = wgt;
      float s0 = st[p], s1 = st[p + 1];
      float mid = __fmul_rn(0.5f, __fadd_rn(s1, s0));
      int bi = (int)floorf(__fdiv_rn(mid, 0.015f));
      bi = bi < 0 ? 0 : (bi > 127 ? 127 : bi);
      bool valid = (mid > __fmul_rn((float)bi, 0.015f)) &&
                   (mid < __fmul_rn((float)(bi + 1), 0.015f));
      if (valid) {
        atomicAdd(&bina[bi], a);
        atomicAdd(&binw[bi], wgt);
        float inner = (-sac[p]) * frcp_(fmaf(mid, mid, 1e-6f));
        atomicAdd(&binr[bi], wgt * rho * inner);
      }
    }
  }
  __syncthreads();

  size_t bb = (size_t)(v * 576 + r) * NB;
  for (int c = 0; c < 2; c++) {
    int b = c * 64 + lane;
    out[O_BA + bb + b] = bina[b];
    out[O_BW + bb + b] = binw[b];
    rad_rows[bb + b] = __fmul_rn(binr[b], wray);
  }
  float opv = binw[lane] + binw[64 + lane];
  for (int d = 32; d; d >>= 1) opv += __shfl_xor(opv, d);
  if (lane == 0) out[O_OP + (size_t)(v * 576 + r)] = opv;
}

// hists gather: one wave per (v,b) output — lane-strided over 576 rays
__global__ void __launch_bounds__(256) k_final(
    const float* __restrict__ rad_rows, float* __restrict__ out) {
  int idx = blockIdx.x * 4 + (threadIdx.x >> 6);
  int lane = threadIdx.x & 63;
  if (idx < 4096) {
    int v = idx >> 7, b = idx & 127;
    const float* base = rad_rows + (size_t)v * 576 * 128 + b;
    float s = 0.0f;
    for (int k = 0; k < 9; k++)
      s += base[(size_t)(lane + 64 * k) * 128];
    for (int d = 32; d; d >>= 1) s += __shfl_xor(s, d);
    if (lane == 0) out[O_HISTS + idx] = s;
  }
}

// ======================= launch ===========================================
extern "C" void kernel_launch(void* const* d_in, const int* in_sizes, int n_in,
                              void* d_out, int out_size, void* d_ws, size_t ws_size,
                              hipStream_t stream) {
  float* out = (float*)d_out;

  const size_t WS_NEED = 5081856u * 4u;
  if (n_in != 7) { hipMemsetAsync(d_out, 0x75, 4, stream); return; }
  static const int want[7] = {384, 192, 64, 64, 1, 1, 1};
  for (int i = 0; i < 7; i++)
    if (in_sizes[i] != want[i]) { hipMemsetAsync(d_out, 0x74, 4, stream); return; }
  if (ws_size < WS_NEED) { hipMemsetAsync(d_out, 0x77, 4, stream); return; }
  (void)out_size;

  uint32_t root[2] = {0u, 42u};
  uint32_t kcf[2][2]; jax_split(root, 2, kcf);
  uint32_t ck[2][2];  jax_split(kcf[0], 2, ck);
  uint32_t crk[5][2]; jax_split(ck[0], 5, crk);
  uint32_t csk[3][2]; jax_split(ck[1], 3, csk);
  uint32_t fk2[2][2]; jax_split(kcf[1], 2, fk2);
  uint32_t frk[5][2]; jax_split(fk2[0], 5, frk);
  uint32_t fsk[3][2]; jax_split(fk2[1], 3, fsk);

  float mc  = (float)cos(60.0 * M_PI / 360.0);
  float omc = 1.0f - mc;
  float sa  = (float)(2.0 * M_PI * (1.0 - (double)mc));

  float* ws = (float*)d_ws;
  size_t off = 0;
  float* dec        = ws + off; off += 768;
  float* c_step_pdf = ws + off; off += 2097152;
  float* c_ray_pdf  = ws + off; off += 16384;
  int*   f_idx      = (int*)(ws + off); off += 2048;
  int*   cnts       = (int*)(ws + off); off += 16384;
  int*   bidx       = (int*)(ws + off); off += 589824;
  float* rad_rows   = ws + off; off += 2359296;

  k_decode<<<1, 256, 0, stream>>>(d_in[0], d_in[1], d_in[2], d_in[3],
                                  d_in[4], d_in[5], d_in[6], dec);
  k_zero<<<64, 256, 0, stream>>>(cnts);
  k_coarse<<<dim3(512, 32), 64, 0, stream>>>(dec,
      mkk(crk[0]), mkk(crk[1]), mkk(csk[0]), mc, omc, c_step_pdf, c_ray_pdf, out);
  k_raycat<<<dim3(64, 32), 64, 0, stream>>>(c_ray_pdf, mkk(frk[2]), f_idx, cnts);
  k_stepcat<<<dim3(576, 32), 64, 0, stream>>>(c_step_pdf, f_idx, mkk(fsk[1]), bidx);
  k_fine<<<dim3(576, 32), 64, 0, stream>>>(dec, f_idx, cnts, bidx,
      mkk(frk[0]), mkk(frk[1]), mkk(frk[3]), mkk(frk[4]), mkk(fsk[0]), mkk(fsk[2]),
      mc, omc, sa, rad_rows, out);
  k_final<<<1024, 256, 0, stream>>>(rad_rows, out);
}

// Round 8
// 804.489 us; speedup vs baseline: 8.0806x; 1.0114x over previous
//
#include <hip/hip_runtime.h>
#include <stdint.h>
#include <math.h>

// =====================================================================
// NeuS renderer — bit-faithful JAX threefry RNG (partitionable mode).
// R8: categorical-sampler fast path. Gumbel values never reach outputs —
// only argmax indices do. Fast path: argmin_b E_b*exp(-lg_b) with hardware
// __logf/__expf; accept only if all other candidates are > (1+1e-4)*min
// (ballot guard; combined rounding <=1e-5 in log-domain => provably same
// index as exact libm argmax). Rare fallback = bit-identical R7 math on
// the same threefry bits. bidx/f_idx provably unchanged vs R7.
// k_raylog hoists raycat row logits (were recomputed 64x per view).
// Coarse/fine/final unchanged from R7 (attribution discipline).
// =====================================================================

#define NS    512
#define NB    128
#define NCS   257
#define NPS   32
#define NFS   289
#define NFM   288
#define HID   64

// output element offsets (fp32 elements), reference return order
#define O_HISTS  0
#define O_SDF    4096
#define O_NORMAL 5312512
#define O_ALPHA  21237760
#define O_T      26546176
#define O_W      31854592
#define O_BA     37163008
#define O_BW     39522304
#define O_OP     41881600
#define O_RPDF   41900032
#define O_SPDF   41916416

// dec[] layout (fp32 canonical inputs in ws)
#define DEC_RT   0
#define DEC_W1   384
#define DEC_B1   576
#define DEC_W2   640
#define DEC_B2   704
#define DEC_INVS 705
#define DEC_RHO  706
#define DEC_G    707

#define TINYF 1.17549435082228751e-38f

// ---------------- threefry2x32 -------------------------------------------
__host__ __device__ inline void tf2x32(uint32_t k0, uint32_t k1,
                                       uint32_t x0, uint32_t x1,
                                       uint32_t& o0, uint32_t& o1) {
  uint32_t ks2 = k0 ^ k1 ^ 0x1BD11BDAu;
  x0 += k0; x1 += k1;
#define TFR(r) { x0 += x1; x1 = (x1 << (r)) | (x1 >> (32 - (r))); x1 ^= x0; }
  TFR(13) TFR(15) TFR(26) TFR(6)
  x0 += k1;  x1 += ks2 + 1u;
  TFR(17) TFR(29) TFR(16) TFR(24)
  x0 += ks2; x1 += k0 + 2u;
  TFR(13) TFR(15) TFR(26) TFR(6)
  x0 += k0;  x1 += k1 + 3u;
  TFR(17) TFR(29) TFR(16) TFR(24)
  x0 += k1;  x1 += ks2 + 4u;
  TFR(13) TFR(15) TFR(26) TFR(6)
  x0 += ks2; x1 += k0 + 5u;
#undef TFR
  o0 = x0; o1 = x1;
}

__device__ inline uint32_t rbits(uint2 k, uint32_t i) {
  uint32_t a, b; tf2x32(k.x, k.y, 0u, i, a, b);
  return a ^ b;
}

__device__ inline float u01(uint32_t bits) {
  return __uint_as_float(0x3f800000u | (bits >> 9)) - 1.0f;
}
__device__ inline float gumbelf(uint32_t bits) {       // exact (fallback)
  float f = u01(bits);
  float u = (f > 0.0f) ? f : TINYF;
  return -logf(-logf(u));
}
__device__ inline float sigmoidf_(float x) {           // libm-exact
  return __fdiv_rn(1.0f, __fadd_rn(1.0f, expf(-x)));
}
__device__ inline float softplusf_(float x) {          // libm-exact
  return __fadd_rn(fmaxf(x, 0.0f), log1pf(expf(-fabsf(x))));
}
__device__ inline float frcp_(float x) { return __builtin_amdgcn_rcpf(x); }
__device__ inline float fsig_(float x) { return frcp_(1.0f + __expf(-x)); }
__device__ inline void argmax_reduce64(float& best, int& bi) {
  for (int off = 1; off < 64; off <<= 1) {
    float ob = __shfl_xor(best, off);
    int   oi = __shfl_xor(bi, off);
    if (ob > best || (ob == best && oi < bi)) { best = ob; bi = oi; }
  }
}
__device__ inline void argmin_reduce64(float& best, int& bi) {
  for (int off = 1; off < 64; off <<= 1) {
    float ob = __shfl_xor(best, off);
    int   oi = __shfl_xor(bi, off);
    if (ob < best || (ob == best && oi < bi)) { best = ob; bi = oi; }
  }
}

// ---------------- host key derivation (jax.random.split) ------------------
static void jax_split(const uint32_t k[2], int n, uint32_t out[][2]) {
  for (int j = 0; j < n; j++)
    tf2x32(k[0], k[1], 0u, (uint32_t)j, out[j][0], out[j][1]);
}
static inline uint2 mkk(const uint32_t k[2]) { return make_uint2(k[0], k[1]); }

// ======================= kernels ==========================================
__device__ inline float ld_as(const void* p, int i, int isbf) {
  if (isbf) {
    uint16_t h = ((const uint16_t*)p)[i];
    return __uint_as_float(((uint32_t)h) << 16);
  }
  return ((const float*)p)[i];
}

__global__ void k_decode(const void* Rt, const void* W1, const void* b1,
                         const void* w2, const void* b2, const void* invs,
                         const void* rho, float* dec) {
  __shared__ int sflag;
  if (threadIdx.x == 0) {
    float errF = 0.0f, errB = 0.0f;
    for (int v = 0; v < 8; v++)
      for (int row = 0; row < 3; row++) {
        float nF = 0.0f, nB = 0.0f;
        for (int j = 0; j < 3; j++) {
          float aF = ld_as(Rt, v * 12 + row * 4 + j, 0); nF += aF * aF;
          float aB = ld_as(Rt, v * 12 + row * 4 + j, 1); nB += aB * aB;
        }
        errF += fabsf(nF - 1.0f); errB += fabsf(nB - 1.0f);
      }
    int pickF = (errF == errF) && (!(errB == errB) || errF < errB);
    sflag = pickF ? 0 : 1;
  }
  __syncthreads();
  int f = sflag, t = threadIdx.x;
  for (int i = t; i < 384; i += 256) dec[DEC_RT + i] = ld_as(Rt, i, f);
  if (t < 192) dec[DEC_W1 + t] = ld_as(W1, t, f);
  if (t < 64)  dec[DEC_B1 + t] = ld_as(b1, t, f);
  if (t < 64)  dec[DEC_W2 + t] = ld_as(w2, t, f);
  if (t == 0) {
    dec[DEC_B2]   = ld_as(b2, 0, f);
    dec[DEC_INVS] = ld_as(invs, 0, f);
    dec[DEC_RHO]  = ld_as(rho, 0, f);
    float G = 0.0f;
    for (int j = 0; j < 64; j++) {
      float wx = ld_as(W1, j, f), wy = ld_as(W1, 64 + j, f), wz = ld_as(W1, 128 + j, f);
      G += fabsf(ld_as(w2, j, f)) * sqrtf(wx * wx + wy * wy + wz * wz);
    }
    dec[DEC_G] = G * 1.02f + 0.001f;
  }
}

__global__ void k_zero(int* __restrict__ cnts) {
  int i = blockIdx.x * 256 + threadIdx.x;
  if (i < 16384) cnts[i] = 0;
}

// row logits for ray categorical: lg exact-libm (fallback), ew fast (guarded)
__global__ void k_raylog(const float* __restrict__ crp,
                         float* __restrict__ lg, float* __restrict__ ew) {
  int i = blockIdx.x * 256 + threadIdx.x;
  if (i < 16384) {
    float l = logf(__fadd_rn(crp[i], 1e-6f));
    lg[i] = l;
    ew[i] = __expf(-l);
  }
}

// one 64-lane block per coarse ray — two-tier MLP, bit-exact outputs (R7)
__global__ void __launch_bounds__(64) k_coarse(
    const float* __restrict__ dec,
    uint2 k_ru, uint2 k_rv, uint2 k_eta, float mc, float omc,
    float* __restrict__ c_step_pdf, float* __restrict__ c_ray_pdf,
    float* __restrict__ out) {
  int r = blockIdx.x, v = blockIdx.y, lane = threadIdx.x;
  __shared__ float4 sW4[64];
  __shared__ float  sw2[64];
  __shared__ float ss[NCS], sfa[NCS], sfe[NCS], salpha[256], sflagf[256];
  __shared__ int   slist[NCS], scls[256];
  if (lane < 64) {
    sW4[lane] = make_float4(dec[DEC_W1 + lane], dec[DEC_W1 + 64 + lane],
                            dec[DEC_W1 + 128 + lane], dec[DEC_B1 + lane]);
    sw2[lane] = dec[DEC_W2 + lane];
  }
  float b2 = dec[DEC_B2];
  float G  = dec[DEC_G];
  float Gm = fminf(1000.0f, G);
  float alpha_c = __fsub_rn(1.0f, __fdiv_rn(1.0f, __fadd_rn(1.0f, 1e-6f)));

  uint32_t li = (uint32_t)(v * NS + r);
  float un = (float)(r >> 3), vn = (float)(r & 7);
  float ru = __fdiv_rn(__fadd_rn(un, u01(rbits(k_ru, li))), 64.0f);
  float rv = __fdiv_rn(__fadd_rn(vn, u01(rbits(k_rv, li))), 8.0f);
  float phi = __fmul_rn(ru, (float)(2.0 * M_PI));
  float ct  = __fadd_rn(__fmul_rn(rv, omc), mc);
  float stq = sqrtf(fmaxf(__fsub_rn(1.0f, __fmul_rn(ct, ct)), 0.0f));
  float dc0 = __fmul_rn(stq, cosf(phi));
  float dc1 = __fmul_rn(stq, sinf(phi));
  const float* Rv = dec + DEC_RT + v * 12;
  float o0 = Rv[3], o1 = Rv[7], o2 = Rv[11];
  float d0 = dc0 * Rv[0] + dc1 * Rv[1] + ct * Rv[2];
  float d1 = dc0 * Rv[4] + dc1 * Rv[5] + ct * Rv[6];
  float d2 = dc0 * Rv[8] + dc1 * Rv[9] + ct * Rv[10];

  for (int p = lane; p < NCS; p += 64) {
    float sp;
    if (p == 256) sp = __fmul_rn(0.015f, 128.0f);
    else {
      int b = p >> 1;
      float eb = __fmul_rn(0.015f, (float)b);
      if (p & 1) {
        float u = u01(rbits(k_eta, li * 128u + (uint32_t)b));
        sp = __fadd_rn(eb, __fmul_rn(u, 0.015f));
      } else sp = eb;
    }
    ss[p] = sp;
  }
  __syncthreads();

  for (int p = lane; p < 256; p += 64) {
    float s0 = ss[p], s1 = ss[p + 1];
    float ax = __fadd_rn(o0, __fmul_rn(s0, d0)), bx = __fadd_rn(o0, __fmul_rn(s1, d0));
    float ay = __fadd_rn(o1, __fmul_rn(s0, d1)), by = __fadd_rn(o1, __fmul_rn(s1, d1));
    float az = __fadd_rn(o2, __fmul_rn(s0, d2)), bz = __fadd_rn(o2, __fmul_rn(s1, d2));
    float mx = __fmul_rn(0.5f, __fadd_rn(ax, bx));
    float my = __fmul_rn(0.5f, __fadd_rn(ay, by));
    float mz = __fmul_rn(0.5f, __fadd_rn(az, bz));
    float n2 = __fadd_rn(__fadd_rn(__fmul_rn(mx, mx), __fmul_rn(my, my)), __fmul_rn(mz, mz));
    bool ins = (sqrtf(n2) < 1.0f) && (mz > 0.0f);
    sflagf[p] = ins ? 1.0f : 0.0f;
  }
  __syncthreads();

  int ncnt = 0;
  for (int c = 0; c < 5; c++) {
    int p = c * 64 + lane;
    bool need = false;
    if (p < NCS) {
      bool f0 = (p >= 1) ? (sflagf[p - 1] != 0.0f) : false;
      bool f1 = (p < 256) ? (sflagf[p] != 0.0f) : false;
      bool f2 = (p + 1 < 256) ? (sflagf[p + 1] != 0.0f) : false;
      need = f0 || f1 || f2;
    }
    unsigned long long m = __ballot(need);
    int idx = ncnt + __popcll(m & ((1ull << lane) - 1ull));
    if (need) slist[idx] = p;
    ncnt += __popcll(m);
  }
  __syncthreads();

  for (int k = lane; k < ncnt; k += 64) {
    int p = slist[k];
    float sp = ss[p];
    float px = fmaf(sp, d0, o0);
    float py = fmaf(sp, d1, o1);
    float pz = fmaf(sp, d2, o2);
    float acc = 0.0f;
    for (int j = 0; j < HID; j++) {
      float4 q = sW4[j];
      float t = fmaf(px, q.x, fmaf(py, q.y, fmaf(pz, q.z, q.w)));
      float e = __expf(-fabsf(t));
      acc = fmaf(fmaxf(t, 0.0f) + __logf(1.0f + e), sw2[j], acc);
    }
    sfa[p] = acc + b2;
  }
  __syncthreads();

  for (int p = lane; p < 256; p += 64) {
    int cls = 0;
    if (sflagf[p] != 0.0f) {
      float delta = __fsub_rn(ss[p + 1], ss[p]);
      float Bd = 0.5f * delta * Gm * 1.01f + 1e-6f;
      float ma = 0.5f * (sfa[p] + sfa[p + 1]);
      float margin = Bd + 0.02f;
      if (ma - margin > 0.28f)       cls = 1;
      else if (ma + margin < -0.52f) cls = 2;
      else                            cls = 3;
    }
    scls[p] = cls;
  }
  __syncthreads();

  int ecnt = 0;
  for (int c = 0; c < 5; c++) {
    int p = c * 64 + lane;
    bool need = false;
    if (p < NCS) {
      bool f0 = (p >= 1) ? (scls[p - 1] == 3) : false;
      bool f1 = (p < 256) ? (scls[p] == 3) : false;
      bool f2 = (p + 1 < 256) ? (scls[p + 1] == 3) : false;
      need = f0 || f1 || f2;
    }
    unsigned long long m = __ballot(need);
    int idx = ecnt + __popcll(m & ((1ull << lane) - 1ull));
    if (need) slist[idx] = p;
    ecnt += __popcll(m);
  }
  __syncthreads();

  for (int k = lane; k < ecnt; k += 64) {
    int p = slist[k];
    float sp = ss[p];
    float px = __fadd_rn(o0, __fmul_rn(sp, d0));
    float py = __fadd_rn(o1, __fmul_rn(sp, d1));
    float pz = __fadd_rn(o2, __fmul_rn(sp, d2));
    float acc = 0.0f;
    for (int j = 0; j < HID; j++) {
      float4 q = sW4[j];
      float t = fmaf(px, q.x, fmaf(py, q.y, fmaf(pz, q.z, q.w)));
      acc = fmaf(softplusf_(t), sw2[j], acc);
    }
    sfe[p] = __fadd_rn(acc, b2);
  }
  __syncthreads();

  for (int p = lane; p < 256; p += 64) {
    int cls = scls[p];
    float a;
    if (cls == 0)      a = 0.0f;
    else if (cls == 1) a = alpha_c;
    else if (cls == 2) a = 1.0f;
    else {
      float s0 = ss[p], s1 = ss[p + 1];
      float f0 = sfe[p], f1 = sfe[p + 1];
      float delta = __fsub_rn(s1, s0);
      float mid_sdf = __fmul_rn(0.5f, __fadd_rn(f1, f0));
      float cosv = __fdiv_rn(__fsub_rn(f1, f0), __fadd_rn(delta, 1e-6f));
      float pcos = 0.0f;
      if (p > 0)
        pcos = __fdiv_rn(__fsub_rn(f0, sfe[p - 1]),
                         __fadd_rn(__fsub_rn(s0, ss[p - 1]), 1e-6f));
      float cc = fminf(fmaxf(fminf(pcos, cosv), -1000.0f), 0.0f);
      float dsdf = __fmul_rn(__fmul_rn(0.5f, cc), delta);
      float pT = sigmoidf_(__fmul_rn(64.0f, __fsub_rn(mid_sdf, dsdf)));
      float nT = sigmoidf_(__fmul_rn(64.0f, __fadd_rn(mid_sdf, dsdf)));
      a = __fmul_rn(__fsub_rn(1.0f, __fdiv_rn(nT, __fadd_rn(pT, 1e-6f))), 1.0f);
    }
    salpha[p] = a;
  }
  __syncthreads();

  if (lane == 0) {
    float T = 1.0f, rsum = 0.0f;
    int base = (v * NS + r) * NB;
    for (int b = 0; b < NB; b++) {
      float a0 = salpha[2 * b], a1 = salpha[2 * b + 1];
      float w0 = __fmul_rn(a0, T);
      float om = __fsub_rn(1.0f, a0);
      T = __fmul_rn(T, __fadd_rn(__fmul_rn(om, om), 1e-6f));
      float w1 = __fmul_rn(a1, T);
      om = __fsub_rn(1.0f, a1);
      T = __fmul_rn(T, __fadd_rn(__fmul_rn(om, om), 1e-6f));
      float spdf = __fadd_rn(w0, w1);
      c_step_pdf[base + b] = spdf;
      out[O_SPDF + base + b] = spdf;
      rsum = __fadd_rn(rsum, spdf);
    }
    c_ray_pdf[v * NS + r] = rsum;
    out[O_RPDF + v * NS + r] = rsum;
  }
}

// ray categorical: fast ratio argmin + guard; fallback = exact R7 math
__global__ void __launch_bounds__(64) k_raycat(
    const float* __restrict__ ray_lg, const float* __restrict__ ray_ew,
    uint2 kg, int* __restrict__ f_idx, int* __restrict__ cnts) {
  int p = blockIdx.x, v = blockIdx.y, lane = threadIdx.x;
  uint32_t rowbase = ((uint32_t)p * 32u + (uint32_t)v) * 512u;
  const float* lgrow = ray_lg + v * 512;
  const float* ewrow = ray_ew + v * 512;
  float rc[8];
  float m1 = INFINITY; int i1 = 0;
  for (int k = 0; k < 8; k++) {
    int n = lane + 64 * k;
    uint32_t bits = rbits(kg, rowbase + (uint32_t)n);
    float f = u01(bits);
    float u = (f > 0.0f) ? f : TINYF;
    float E = -__logf(u);
    float rr = E * ewrow[n];
    rc[k] = rr;
    if (rr < m1) { m1 = rr; i1 = n; }
  }
  argmin_reduce64(m1, i1);
  float thr = m1 * (1.0f + 1e-4f);
  bool near = false;
  for (int k = 0; k < 8; k++)
    near = near || ((lane + 64 * k != i1) && (rc[k] <= thr));
  if (__ballot(near)) {
    float best = -INFINITY; int bi = 0;        // exact fallback (R7 ops)
    for (int n = lane; n < 512; n += 64) {
      float val = __fadd_rn(gumbelf(rbits(kg, rowbase + (uint32_t)n)), lgrow[n]);
      if (val > best) { best = val; bi = n; }
    }
    argmax_reduce64(best, bi);
    i1 = bi;
  }
  if (lane == 0) {
    f_idx[v * 64 + p] = i1;
    atomicAdd(&cnts[v * 512 + i1], 1);
  }
}

// step categorical: fast ratio argmin + guard; fallback = exact R7 math
__global__ void __launch_bounds__(64) k_stepcat(
    const float* __restrict__ c_step_pdf, const int* __restrict__ f_idx,
    uint2 kg, int* __restrict__ bidx) {
  int r = blockIdx.x, v = blockIdx.y, lane = threadIdx.x;
  int n = (r < 512) ? r : f_idx[v * 64 + (r - 512)];
  const float* pdfrow = c_step_pdf + (v * 512 + n) * 128;
  float lg0 = logf(__fadd_rn(pdfrow[lane], 1e-6f));       // exact (fallback)
  float lg1 = logf(__fadd_rn(pdfrow[64 + lane], 1e-6f));
  float ew0 = __expf(-lg0), ew1 = __expf(-lg1);           // fast (guarded)
  for (int p = 0; p < 32; p++) {
    uint32_t base = (((uint32_t)p * 32u + (uint32_t)v) * 576u + (uint32_t)r) * 128u;
    uint32_t bits0 = rbits(kg, base + (uint32_t)lane);
    uint32_t bits1 = rbits(kg, base + 64u + (uint32_t)lane);
    float f0 = u01(bits0), f1 = u01(bits1);
    float u0 = (f0 > 0.0f) ? f0 : TINYF;
    float u1 = (f1 > 0.0f) ? f1 : TINYF;
    float r0 = (-__logf(u0)) * ew0;
    float r1 = (-__logf(u1)) * ew1;
    float m1 = r0; int i1 = lane;
    if (r1 < m1) { m1 = r1; i1 = 64 + lane; }
    argmin_reduce64(m1, i1);
    float thr = m1 * (1.0f + 1e-4f);
    bool near = ((lane != i1) && (r0 <= thr)) ||
                ((64 + lane != i1) && (r1 <= thr));
    if (__ballot(near)) {
      float v0 = __fadd_rn(gumbelf(bits0), lg0);          // exact fallback
      float v1 = __fadd_rn(gumbelf(bits1), lg1);
      float best = v0; int bi = lane;
      if (v1 > best) { best = v1; bi = 64 + lane; }
      argmax_reduce64(best, bi);
      i1 = bi;
    }
    if (lane == 0) bidx[(v * 576 + r) * 32 + p] = i1;
  }
}

// one 64-lane block per fine ray — parallel merge/compaction/scan, fast MLP
__global__ void __launch_bounds__(64) k_fine(
    const float* __restrict__ dec, const int* __restrict__ f_idx,
    const int* __restrict__ cnts, const int* __restrict__ bidx,
    uint2 k_ru, uint2 k_rv, uint2 k_rup, uint2 k_rvp, uint2 k_eta, uint2 k_us,
    float mc, float omc, float sa,
    float* __restrict__ rad_rows, float* __restrict__ out) {
  int r = blockIdx.x, v = blockIdx.y, lane = threadIdx.x;
  __shared__ float4 sW4[64];
  __shared__ float  sw2[64];
  __shared__ float sb[NCS], pe[NPS], st[NFS];
  __shared__ float sal[NFM], sac[NFM], sT[NFM];
  __shared__ int   slist[NFM];
  __shared__ float bina[NB], binw[NB], binr[NB];
  if (lane < 64) {
    sW4[lane] = make_float4(dec[DEC_W1 + lane], dec[DEC_W1 + 64 + lane],
                            dec[DEC_W1 + 128 + lane], dec[DEC_B1 + lane]);
    sw2[lane] = dec[DEC_W2 + lane];
  }
  bina[lane] = 0.0f; binw[lane] = 0.0f; binr[lane] = 0.0f;
  bina[64 + lane] = 0.0f; binw[64 + lane] = 0.0f; binr[64 + lane] = 0.0f;
  float b2 = dec[DEC_B2], inv_s = dec[DEC_INVS], rho = dec[DEC_RHO];

  int n; float ruB, rvB;
  if (r < 512) {
    n = r;
    ruB = u01(rbits(k_ru, (uint32_t)(v * 512 + r)));
    rvB = u01(rbits(k_rv, (uint32_t)(v * 512 + r)));
  } else {
    int p = r - 512;
    n = f_idx[v * 64 + p];
    ruB = u01(rbits(k_rup, (uint32_t)(v * 64 + p)));
    rvB = u01(rbits(k_rvp, (uint32_t)(v * 64 + p)));
  }
  float un = (float)(n >> 3), vn = (float)(n & 7);
  float ru = __fdiv_rn(__fadd_rn(un, ruB), 64.0f);
  float rv = __fdiv_rn(__fadd_rn(vn, rvB), 8.0f);
  float phi = __fmul_rn(ru, (float)(2.0 * M_PI));
  float ct  = __fadd_rn(__fmul_rn(rv, omc), mc);
  float stq = sqrtf(fmaxf(__fsub_rn(1.0f, __fmul_rn(ct, ct)), 0.0f));
  float dc0 = __fmul_rn(stq, cosf(phi));
  float dc1 = __fmul_rn(stq, sinf(phi));
  const float* Rv = dec + DEC_RT + v * 12;
  float o0 = Rv[3], o1 = Rv[7], o2 = Rv[11];
  float d0 = dc0 * Rv[0] + dc1 * Rv[1] + ct * Rv[2];
  float d1 = dc0 * Rv[4] + dc1 * Rv[5] + ct * Rv[6];
  float d2 = dc0 * Rv[8] + dc1 * Rv[9] + ct * Rv[10];
  float wb = __fdiv_rn(1.0f, __fmul_rn(__fadd_rn((float)cnts[v * 512 + n], 1.0f), 512.0f));
  float wray = __fmul_rn(__fmul_rn(wb, ct), sa);

  uint32_t li = (uint32_t)(v * 576 + r);
  for (int p = lane; p < NCS; p += 64) {
    float sp;
    if (p == 256) sp = __fmul_rn(0.015f, 128.0f);
    else {
      int b = p >> 1;
      float eb = __fmul_rn(0.015f, (float)b);
      if (p & 1) {
        float u = u01(rbits(k_eta, li * 128u + (uint32_t)b));
        sp = __fadd_rn(eb, __fmul_rn(u, 0.015f));
      } else sp = eb;
    }
    sb[p] = sp;
  }
  if (lane < NPS) {
    int b = bidx[(v * 576 + r) * 32 + lane];
    float le = __fmul_rn(0.015f, (float)b);
    float u = u01(rbits(k_us, li * 32u + (uint32_t)lane));
    pe[lane] = __fadd_rn(le, __fmul_rn(u, 0.015f));
  }
  __syncthreads();

  for (int c = 0; c < 5; c++) {
    int p = c * 64 + lane;
    if (p < NCS) {
      float x = sb[p];
      int cntlt = 0;
      for (int j = 0; j < NPS; j++) cntlt += (pe[j] < x) ? 1 : 0;
      st[p + cntlt] = x;
    }
  }
  if (lane < NPS) {
    float x = pe[lane];
    int lo = 0, hi = NCS;
    while (lo < hi) { int m = (lo + hi) >> 1; if (sb[m] <= x) lo = m + 1; else hi = m; }
    int rk = 0;
    for (int j = 0; j < NPS; j++) {
      float y = pe[j];
      rk += (y < x || (y == x && j < lane)) ? 1 : 0;
    }
    st[lo + rk] = x;
  }
  __syncthreads();

  size_t obase = (size_t)(v * 576 + r) * NFM;
  int cnt = 0;
  for (int c = 0; c < 5; c++) {
    int p = c * 64 + lane;
    bool f = false;
    if (p < NFM) {
      float s0 = st[p], s1 = st[p + 1];
      float mid = __fmul_rn(0.5f, __fadd_rn(s1, s0));
      float px = __fadd_rn(o0, __fmul_rn(mid, d0));
      float py = __fadd_rn(o1, __fmul_rn(mid, d1));
      float pz = __fadd_rn(o2, __fmul_rn(mid, d2));
      float n2 = __fadd_rn(__fadd_rn(__fmul_rn(px, px), __fmul_rn(py, py)), __fmul_rn(pz, pz));
      f = (sqrtf(n2) < 1.0f) && (pz > 0.0f);
      sal[p] = 0.0f; sac[p] = 0.0f;
      if (!f) {
        out[O_SDF + obase + p] = 0.0f;
        out[O_ALPHA + obase + p] = 0.0f;
        size_t nb3 = (obase + p) * 3;
        out[O_NORMAL + nb3] = 0.0f;
        out[O_NORMAL + nb3 + 1] = 0.0f;
        out[O_NORMAL + nb3 + 2] = 0.0f;
      }
    }
    unsigned long long m = __ballot(f);
    int idx = cnt + __popcll(m & ((1ull << lane) - 1ull));
    if (f) slist[idx] = p;
    cnt += __popcll(m);
  }
  __syncthreads();

  for (int k = lane; k < cnt; k += 64) {
    int p = slist[k];
    float s0 = st[p], s1 = st[p + 1];
    float delta = s1 - s0;
    float mid = 0.5f * (s1 + s0);
    float px = fmaf(mid, d0, o0);
    float py = fmaf(mid, d1, o1);
    float pz = fmaf(mid, d2, o2);
    float acc = 0.0f, g0 = 0.0f, g1 = 0.0f, g2 = 0.0f;
    for (int j = 0; j < HID; j++) {
      float4 q = sW4[j];
      float t = fmaf(px, q.x, fmaf(py, q.y, fmaf(pz, q.z, q.w)));
      float e = __expf(-fabsf(t));
      float w2j = sw2[j];
      acc = fmaf(fmaxf(t, 0.0f) + __logf(1.0f + e), w2j, acc);
      float rr = frcp_(1.0f + e);
      float sg = (t >= 0.0f) ? rr : e * rr;
      float m = sg * w2j;
      g0 = fmaf(m, q.x, g0);
      g1 = fmaf(m, q.y, g1);
      g2 = fmaf(m, q.z, g2);
    }
    float sdf = acc + b2;
    float cosr = fmaf(d0, g0, fmaf(d1, g1, d2 * g2));
    float ac = -fmaxf(fmaf(-cosr, 0.5f, 0.5f), 0.0f);
    float dsdf = 0.5f * ac * delta;
    float pT = fsig_(inv_s * (sdf - dsdf));
    float nT = fsig_(inv_s * (sdf + dsdf));
    float alpha = 1.0f - nT * frcp_(pT + 1e-6f);
    sal[p] = alpha; sac[p] = ac;
    out[O_SDF + obase + p] = sdf;
    size_t nb3 = (obase + p) * 3;
    out[O_NORMAL + nb3]     = g0;
    out[O_NORMAL + nb3 + 1] = g1;
    out[O_NORMAL + nb3 + 2] = g2;
    out[O_ALPHA + obase + p] = alpha;
  }
  __syncthreads();

  {
    int q0 = lane * 5, q1 = q0 + 5 > NFM ? NFM : q0 + 5;
    float lp = 1.0f;
    for (int q = q0; q < q1; q++) { float om = 1.0f - sal[q]; lp *= om * om; }
    float x = lp;
    for (int d = 1; d < 64; d <<= 1) {
      float y = __shfl_up(x, d);
      if (lane >= d) x *= y;
    }
    float excl = __shfl_up(x, 1);
    if (lane == 0) excl = 1.0f;
    float T = excl;
    for (int q = q0; q < q1; q++) {
      sT[q] = T;
      float om = 1.0f - sal[q];
      T *= om * om;
    }
  }
  __syncthreads();

  for (int c = 0; c < 5; c++) {
    int p = c * 64 + lane;
    if (p < NFM) {
      float T = sT[p], a = sal[p];
      float wgt = a * T;
      out[O_T + obase + p] = T;
      out[O_W + obase + p] = wgt;
      float s0 = st[p], s1 = st[p + 1];
      float mid = __fmul_rn(0.5f, __fadd_rn(s1, s0));
      int bi = (int)floorf(__fdiv_rn(mid, 0.015f));
      bi = bi < 0 ? 0 : (bi > 127 ? 127 : bi);
      bool valid = (mid > __fmul_rn((float)bi, 0.015f)) &&
                   (mid < __fmul_rn((float)(bi + 1), 0.015f));
      if (valid) {
        atomicAdd(&bina[bi], a);
        atomicAdd(&binw[bi], wgt);
        float inner = (-sac[p]) * frcp_(fmaf(mid, mid, 1e-6f));
        atomicAdd(&binr[bi], wgt * rho * inner);
      }
    }
  }
  __syncthreads();

  size_t bb = (size_t)(v * 576 + r) * NB;
  for (int c = 0; c < 2; c++) {
    int b = c * 64 + lane;
    out[O_BA + bb + b] = bina[b];
    out[O_BW + bb + b] = binw[b];
    rad_rows[bb + b] = __fmul_rn(binr[b], wray);
  }
  float opv = binw[lane] + binw[64 + lane];
  for (int d = 32; d; d >>= 1) opv += __shfl_xor(opv, d);
  if (lane == 0) out[O_OP + (size_t)(v * 576 + r)] = opv;
}

// hists gather: one wave per (v,b) output
__global__ void __launch_bounds__(256) k_final(
    const float* __restrict__ rad_rows, float* __restrict__ out) {
  int idx = blockIdx.x * 4 + (threadIdx.x >> 6);
  int lane = threadIdx.x & 63;
  if (idx < 4096) {
    int v = idx >> 7, b = idx & 127;
    const float* base = rad_rows + (size_t)v * 576 * 128 + b;
    float s = 0.0f;
    for (int k = 0; k < 9; k++)
      s += base[(size_t)(lane + 64 * k) * 128];
    for (int d = 32; d; d >>= 1) s += __shfl_xor(s, d);
    if (lane == 0) out[O_HISTS + idx] = s;
  }
}

// ======================= launch ===========================================
extern "C" void kernel_launch(void* const* d_in, const int* in_sizes, int n_in,
                              void* d_out, int out_size, void* d_ws, size_t ws_size,
                              hipStream_t stream) {
  float* out = (float*)d_out;

  const size_t WS_NEED = 5114624u * 4u;
  if (n_in != 7) { hipMemsetAsync(d_out, 0x75, 4, stream); return; }
  static const int want[7] = {384, 192, 64, 64, 1, 1, 1};
  for (int i = 0; i < 7; i++)
    if (in_sizes[i] != want[i]) { hipMemsetAsync(d_out, 0x74, 4, stream); return; }
  if (ws_size < WS_NEED) { hipMemsetAsync(d_out, 0x77, 4, stream); return; }
  (void)out_size;

  uint32_t root[2] = {0u, 42u};
  uint32_t kcf[2][2]; jax_split(root, 2, kcf);
  uint32_t ck[2][2];  jax_split(kcf[0], 2, ck);
  uint32_t crk[5][2]; jax_split(ck[0], 5, crk);
  uint32_t csk[3][2]; jax_split(ck[1], 3, csk);
  uint32_t fk2[2][2]; jax_split(kcf[1], 2, fk2);
  uint32_t frk[5][2]; jax_split(fk2[0], 5, frk);
  uint32_t fsk[3][2]; jax_split(fk2[1], 3, fsk);

  float mc  = (float)cos(60.0 * M_PI / 360.0);
  float omc = 1.0f - mc;
  float sa  = (float)(2.0 * M_PI * (1.0 - (double)mc));

  float* ws = (float*)d_ws;
  size_t off = 0;
  float* dec        = ws + off; off += 768;
  float* c_step_pdf = ws + off; off += 2097152;
  float* c_ray_pdf  = ws + off; off += 16384;
  float* ray_lg     = ws + off; off += 16384;
  float* ray_ew     = ws + off; off += 16384;
  int*   f_idx      = (int*)(ws + off); off += 2048;
  int*   cnts       = (int*)(ws + off); off += 16384;
  int*   bidx       = (int*)(ws + off); off += 589824;
  float* rad_rows   = ws + off; off += 2359296;   // total 5,114,624 floats

  k_decode<<<1, 256, 0, stream>>>(d_in[0], d_in[1], d_in[2], d_in[3],
                                  d_in[4], d_in[5], d_in[6], dec);
  k_zero<<<64, 256, 0, stream>>>(cnts);
  k_coarse<<<dim3(512, 32), 64, 0, stream>>>(dec,
      mkk(crk[0]), mkk(crk[1]), mkk(csk[0]), mc, omc, c_step_pdf, c_ray_pdf, out);
  k_raylog<<<64, 256, 0, stream>>>(c_ray_pdf, ray_lg, ray_ew);
  k_raycat<<<dim3(64, 32), 64, 0, stream>>>(ray_lg, ray_ew, mkk(frk[2]), f_idx, cnts);
  k_stepcat<<<dim3(576, 32), 64, 0, stream>>>(c_step_pdf, f_idx, mkk(fsk[1]), bidx);
  k_fine<<<dim3(576, 32), 64, 0, stream>>>(dec, f_idx, cnts, bidx,
      mkk(frk[0]), mkk(frk[1]), mkk(frk[3]), mkk(frk[4]), mkk(fsk[0]), mkk(fsk[2]),
      mc, omc, sa, rad_rows, out);
  k_final<<<1024, 256, 0, stream>>>(rad_rows, out);
}